// Round 3
// baseline (781.115 us; speedup 1.0000x reference)
//
#include <hip/hip_runtime.h>
#include <hip/hip_bf16.h>

#define T_LEN   16000
#define NT4     4000        // T_LEN/4
#define NB      16
#define NTB     125         // T_LEN / 128 (kC tiling)
#define NTE     250         // T_LEN / 64  (kE tiling)
#define NTP     250         // T_LEN / 64  (P1 tiling)
#define EPSV    1e-8f

typedef short bf16x8 __attribute__((ext_vector_type(8)));
typedef float f32x4  __attribute__((ext_vector_type(4)));

__device__ __forceinline__ ushort bf16_rn(float f) {
    uint u = __float_as_uint(f);
    uint r = (u + 0x7FFFu + ((u >> 16) & 1u)) >> 16;
    return (ushort)r;
}
__device__ __forceinline__ float bf16_tof(ushort h) {
    return __uint_as_float(((uint)h) << 16);
}
__device__ __forceinline__ void bfsplit(float v, ushort& h, ushort& l) {
    h = bf16_rn(v);
    l = bf16_rn(v - bf16_tof(h));
}
__device__ __forceinline__ float f4c(const float4& v, int i) {
    return i == 0 ? v.x : i == 1 ? v.y : i == 2 ? v.z : v.w;
}
__device__ __forceinline__ int swz(int u, int t) {
    return u ^ ((t ^ (t >> 3)) & 7);
}

// ---------------------------------------------------------------------------
// NEW Pass 1: read X [b][c][t] once; emit (a) per-(b,c) partial s,q over this
// 64-t tile, (b) transposed bf16 hi/lo planes Xt[b][t][256].
// grid (250, 16) x 256 thr.
// ---------------------------------------------------------------------------
__global__ __launch_bounds__(256) void kP1_split(
    const float* __restrict__ x,
    ushort* __restrict__ Xth, ushort* __restrict__ Xtl,
    float* __restrict__ sp, float* __restrict__ qp)
{
    const int tt = blockIdx.x;          // 0..249
    const int b  = blockIdx.y;
    const int t0 = tt * 64;
    const int tid = threadIdx.x;
    const int j  = tid & 15;            // t-subcol: t = j*4..+3
    const int cg = tid >> 4;            // 0..15

    __shared__ ushort Hs[64][260];      // [t][c], pad 260 -> ~2-way banks
    __shared__ ushort Ls[64][260];

    #pragma unroll
    for (int p = 0; p < 4; ++p) {
        float4 v[4];
        int cs[4];
        #pragma unroll
        for (int k = 0; k < 4; ++k) {
            cs[k] = k*64 + p*16 + cg;
            v[k] = *(const float4*)(x + ((size_t)(b*256 + cs[k]))*T_LEN + t0 + j*4);
        }
        #pragma unroll
        for (int k = 0; k < 4; ++k) {
            float s4 = 0.f, q4 = 0.f;
            #pragma unroll
            for (int i = 0; i < 4; ++i) {
                const float f = f4c(v[k], i);
                s4 += f; q4 += f*f;
                ushort hh, ll; bfsplit(f, hh, ll);
                Hs[j*4 + i][cs[k]] = hh;
                Ls[j*4 + i][cs[k]] = ll;
            }
            #pragma unroll
            for (int m = 1; m <= 8; m <<= 1) {
                s4 += __shfl_xor(s4, m, 16);
                q4 += __shfl_xor(q4, m, 16);
            }
            if (j == 0) {
                sp[((size_t)b*NTP + tt)*256 + cs[k]] = s4;
                qp[((size_t)b*NTP + tt)*256 + cs[k]] = q4;
            }
        }
    }
    __syncthreads();
    const int w = tid >> 6, l = tid & 63;
    ushort* oh = Xth + ((size_t)b*T_LEN + t0)*256;
    ushort* ol = Xtl + ((size_t)b*T_LEN + t0)*256;
    #pragma unroll
    for (int i = 0; i < 16; ++i) {
        const int t = w*16 + i;
        *(uint2*)(oh + (size_t)t*256 + l*4) = *(const uint2*)&Hs[t][l*4];
        *(uint2*)(ol + (size_t)t*256 + l*4) = *(const uint2*)&Ls[t][l*4];
    }
}

// ---------------------------------------------------------------------------
// Fallback Kernel A: per-(b,c) row sums.
// ---------------------------------------------------------------------------
__global__ __launch_bounds__(256) void kA_rowstats(
    const float* __restrict__ x, float* __restrict__ s, float* __restrict__ q)
{
    const int row = blockIdx.x;
    const float4* x4 = (const float4*)(x + (size_t)row * T_LEN);
    float ss = 0.f, qq = 0.f;
    for (int i = threadIdx.x; i < NT4; i += 256) {
        float4 v = x4[i];
        ss += v.x + v.y + v.z + v.w;
        qq += v.x*v.x + v.y*v.y + v.z*v.z + v.w*v.w;
    }
    #pragma unroll
    for (int off = 32; off; off >>= 1) {
        ss += __shfl_down(ss, off, 64);
        qq += __shfl_down(qq, off, 64);
    }
    __shared__ float rs[4], rq[4];
    const int wid = threadIdx.x >> 6, lane = threadIdx.x & 63;
    if (lane == 0) { rs[wid] = ss; rq[wid] = qq; }
    __syncthreads();
    if (threadIdx.x == 0) {
        s[row] = rs[0] + rs[1] + rs[2] + rs[3];
        q[row] = rq[0] + rq[1] + rq[2] + rq[3];
    }
}

// ---------------------------------------------------------------------------
__device__ __forceinline__ float blockSum256(float v, float* red)
{
    #pragma unroll
    for (int off = 32; off; off >>= 1) v += __shfl_down(v, off, 64);
    __syncthreads();
    if ((threadIdx.x & 63) == 0) red[threadIdx.x >> 6] = v;
    __syncthreads();
    return red[0] + red[1] + red[2] + red[3];
}

// ---------------------------------------------------------------------------
// Kernel B: analytic affine composition -> M (fp32 + bf16 hi/lo), e.
// ntiles>0: fold per-tile partials sArr/qArr ([b][ntiles][256]); else direct.
// ---------------------------------------------------------------------------
__global__ __launch_bounds__(256) void kB_compose(
    const float* __restrict__ sArr,   const float* __restrict__ qArr, int ntiles,
    const float* __restrict__ cue,
    const float* __restrict__ gn_a_w, const float* __restrict__ gn_a_b,
    const float* __restrict__ gn_n_w, const float* __restrict__ gn_n_b,
    const float* __restrict__ f1g_w,  const float* __restrict__ f1g_b,
    const float* __restrict__ f1b_w,  const float* __restrict__ f1b_b,
    const float* __restrict__ ln1_w,  const float* __restrict__ ln1_b,
    const float* __restrict__ conv1_w,const float* __restrict__ cds_w,
    const float* __restrict__ f2g_w,  const float* __restrict__ f2g_b,
    const float* __restrict__ f2b_w,  const float* __restrict__ f2b_b,
    float* __restrict__ Mout, ushort* __restrict__ Mh, ushort* __restrict__ Ml,
    float* __restrict__ eout)
{
    const int b = blockIdx.x;
    const int c = threadIdx.x;           // 0..255
    __shared__ float red[4];
    __shared__ float sh_cue[512];
    __shared__ float sh_a[256], sh_d[256], sh_cue2[256], sh_g2[128];

    sh_cue[c]       = cue[b*512 + c];
    sh_cue[256 + c] = cue[b*512 + 256 + c];
    float sc, qc;
    if (ntiles > 0) {
        sc = 0.f; qc = 0.f;
        for (int i = 0; i < ntiles; ++i) {
            sc += sArr[((size_t)b*ntiles + i)*256 + c];
            qc += qArr[((size_t)b*ntiles + i)*256 + c];
        }
    } else {
        sc = sArr[b*256 + c];
        qc = qArr[b*256 + c];
    }
    __syncthreads();

    const float Ninv = 1.f / (256.f * 16000.f);
    const float Tf = 16000.f;

    float S  = blockSum256(sc, red);
    float Q  = blockSum256(qc, red);
    float mu1 = S * Ninv;
    float var1 = Q * Ninv - mu1 * mu1;
    float r1 = rsqrtf(var1 + EPSV);
    float a1 = gn_a_w[c] * r1;
    float d1 = gn_a_b[c] - mu1 * r1 * gn_a_w[c];

    float S2 = blockSum256(a1*sc + Tf*d1, red);
    float Q2 = blockSum256(a1*a1*qc + 2.f*a1*d1*sc + Tf*d1*d1, red);
    float mu2 = S2 * Ninv;
    float var2 = Q2 * Ninv - mu2 * mu2;
    float r2 = rsqrtf(var2 + EPSV);
    float wn = gn_n_w[c];
    float a2 = wn * r2 * a1;
    float d2 = wn * r2 * (d1 - mu2) + gn_n_b[c];

    float g1 = f1g_b[c], b1 = f1b_b[c];
    for (int k = 0; k < 512; ++k) {
        const float cv = sh_cue[k];
        g1 = fmaf(cv, f1g_w[c*512 + k], g1);
        b1 = fmaf(cv, f1b_w[c*512 + k], b1);
    }
    g1 = fmaxf(g1, 0.f) + 1.f;
    b1 = fmaxf(b1, 0.f);
    float a3 = g1 * a2;
    float d3 = g1 * d2 + b1;

    float S3 = blockSum256(a3*sc + Tf*d3, red);
    float Q3 = blockSum256(a3*a3*qc + 2.f*a3*d3*sc + Tf*d3*d3, red);
    float mu3 = S3 * Ninv;
    float var3 = Q3 * Ninv - mu3 * mu3;
    float r3 = rsqrtf(var3 + EPSV);
    float w1 = ln1_w[c];
    float a4 = w1 * r3 * a3;
    float d4 = w1 * r3 * (d3 - mu3) + ln1_b[c];
    sh_a[c] = a4;
    sh_d[c] = d4;

    float c2 = 0.f;
    for (int k = 0; k < 512; ++k) c2 = fmaf(sh_cue[k], cds_w[c*512 + k], c2);
    sh_cue2[c] = fmaxf(c2, 0.f);
    __syncthreads();

    if (c < 128) {
        float g2 = f2g_b[c], b2 = f2b_b[c];
        for (int k = 0; k < 256; ++k) {
            const float cv = sh_cue2[k];
            g2 = fmaf(cv, f2g_w[c*256 + k], g2);
            b2 = fmaf(cv, f2b_w[c*256 + k], b2);
        }
        g2 = fmaxf(g2, 0.f) + 1.f;
        b2 = fmaxf(b2, 0.f);
        float u = 0.f;
        for (int k = 0; k < 256; ++k) u = fmaf(conv1_w[c*256 + k], sh_d[k], u);
        eout[b*128 + c] = g2 * u + b2;
        sh_g2[c] = g2;
    }
    __syncthreads();

    for (int o = 0; o < 128; ++o) {
        const float m = sh_g2[o] * conv1_w[o*256 + c] * sh_a[c];
        const size_t idx = ((size_t)b*128 + o)*256 + c;
        Mout[idx] = m;
        ushort hh, ll; bfsplit(m, hh, ll);
        Mh[idx] = hh; Ml[idx] = ll;
    }
}

// ---------------------------------------------------------------------------
// NEW Kernel C: stats GEMM, no LDS staging. Tile 128o x 128t, 4 waves.
// A (Mh/Ml) and B (Xth/Xtl) fragments loaded directly from global; each wave
// instruction covers 16 full 64B lines.
// ---------------------------------------------------------------------------
__global__ __launch_bounds__(256) void kC_direct(
    const ushort* __restrict__ Xth, const ushort* __restrict__ Xtl,
    const ushort* __restrict__ Mh, const ushort* __restrict__ Ml,
    const float* __restrict__ e,
    float* __restrict__ s2p, float* __restrict__ q2p)
{
    const int tb = blockIdx.x;         // 0..124
    const int b  = blockIdx.y;
    const int tid  = threadIdx.x;
    const int lane = tid & 63;
    const int wid  = tid >> 6;
    const int o0w = (wid >> 1) * 64;
    const int t0w = (wid & 1) * 64;
    const int sub = lane >> 4;
    const int li  = lane & 15;

    __shared__ float sSp[2][128], sQp[2][128];

    f32x4 acc[4][4];
    #pragma unroll
    for (int i = 0; i < 4; ++i)
        #pragma unroll
        for (int j = 0; j < 4; ++j) acc[i][j] = (f32x4){0.f, 0.f, 0.f, 0.f};

    const ushort* xh = Xth + ((size_t)b*T_LEN + tb*128 + t0w)*256;
    const ushort* xl = Xtl + ((size_t)b*T_LEN + tb*128 + t0w)*256;
    const ushort* mh = Mh + (size_t)b*128*256;
    const ushort* ml = Ml + (size_t)b*128*256;

    #pragma unroll 2
    for (int kk = 0; kk < 256; kk += 32) {
        const int k8 = kk + 8*sub;
        bf16x8 bh[4], bl[4];
        #pragma unroll
        for (int ft = 0; ft < 4; ++ft) {
            const size_t xi = (size_t)(ft*16 + li)*256 + k8;
            bh[ft] = *(const bf16x8*)(xh + xi);
            bl[ft] = *(const bf16x8*)(xl + xi);
        }
        #pragma unroll
        for (int fo = 0; fo < 4; ++fo) {
            const size_t mi = (size_t)(o0w + fo*16 + li)*256 + k8;
            const bf16x8 ah = *(const bf16x8*)(mh + mi);
            const bf16x8 al = *(const bf16x8*)(ml + mi);
            #pragma unroll
            for (int ft = 0; ft < 4; ++ft) {
                acc[fo][ft] = __builtin_amdgcn_mfma_f32_16x16x32_bf16(ah, bh[ft], acc[fo][ft], 0, 0, 0);
                acc[fo][ft] = __builtin_amdgcn_mfma_f32_16x16x32_bf16(al, bh[ft], acc[fo][ft], 0, 0, 0);
                acc[fo][ft] = __builtin_amdgcn_mfma_f32_16x16x32_bf16(ah, bl[ft], acc[fo][ft], 0, 0, 0);
            }
        }
    }

    #pragma unroll
    for (int fo = 0; fo < 4; ++fo) {
        #pragma unroll
        for (int r = 0; r < 4; ++r) {
            const int o = o0w + fo*16 + sub*4 + r;
            const float ev = e[b*128 + o];
            float sv = 0.f, qv = 0.f;
            #pragma unroll
            for (int ft = 0; ft < 4; ++ft) {
                const float z = acc[fo][ft][r] + ev;
                sv += z; qv += z*z;
            }
            #pragma unroll
            for (int m = 1; m <= 8; m <<= 1) {
                sv += __shfl_xor(sv, m, 64);
                qv += __shfl_xor(qv, m, 64);
            }
            if (li == 0) { sSp[wid & 1][o] = sv; sQp[wid & 1][o] = qv; }
        }
    }
    __syncthreads();
    if (tid < 128) {
        s2p[((size_t)b*NTB + tb)*128 + tid] = sSp[0][tid] + sSp[1][tid];
        q2p[((size_t)b*NTB + tb)*128 + tid] = sQp[0][tid] + sQp[1][tid];
    }
}

// ---------------------------------------------------------------------------
// NEW Kernel E: out = F x + h, no LDS. Tile 256o x 64t, 4 waves (o split).
// ---------------------------------------------------------------------------
__global__ __launch_bounds__(256) void kE_direct(
    const ushort* __restrict__ Xth, const ushort* __restrict__ Xtl,
    const ushort* __restrict__ Fh, const ushort* __restrict__ Fl,
    const float* __restrict__ h,
    float* __restrict__ out)
{
    const int tb = blockIdx.x;         // 0..249
    const int b  = blockIdx.y;
    const int tid  = threadIdx.x;
    const int lane = tid & 63;
    const int wid  = tid >> 6;
    const int o0w = wid * 64;
    const int sub = lane >> 4;
    const int li  = lane & 15;
    const int t0  = tb * 64;

    f32x4 acc[4][4];
    #pragma unroll
    for (int i = 0; i < 4; ++i)
        #pragma unroll
        for (int j = 0; j < 4; ++j) acc[i][j] = (f32x4){0.f, 0.f, 0.f, 0.f};

    const ushort* xh = Xth + ((size_t)b*T_LEN + t0)*256;
    const ushort* xl = Xtl + ((size_t)b*T_LEN + t0)*256;
    const ushort* fh = Fh + (size_t)b*256*256;
    const ushort* fl = Fl + (size_t)b*256*256;

    #pragma unroll 2
    for (int kk = 0; kk < 256; kk += 32) {
        const int k8 = kk + 8*sub;
        bf16x8 bh[4], bl[4];
        #pragma unroll
        for (int ft = 0; ft < 4; ++ft) {
            const size_t xi = (size_t)(ft*16 + li)*256 + k8;
            bh[ft] = *(const bf16x8*)(xh + xi);
            bl[ft] = *(const bf16x8*)(xl + xi);
        }
        #pragma unroll
        for (int fo = 0; fo < 4; ++fo) {
            const size_t fi = (size_t)(o0w + fo*16 + li)*256 + k8;
            const bf16x8 ah = *(const bf16x8*)(fh + fi);
            const bf16x8 al = *(const bf16x8*)(fl + fi);
            #pragma unroll
            for (int ft = 0; ft < 4; ++ft) {
                acc[fo][ft] = __builtin_amdgcn_mfma_f32_16x16x32_bf16(ah, bh[ft], acc[fo][ft], 0, 0, 0);
                acc[fo][ft] = __builtin_amdgcn_mfma_f32_16x16x32_bf16(al, bh[ft], acc[fo][ft], 0, 0, 0);
                acc[fo][ft] = __builtin_amdgcn_mfma_f32_16x16x32_bf16(ah, bl[ft], acc[fo][ft], 0, 0, 0);
            }
        }
    }

    #pragma unroll
    for (int fo = 0; fo < 4; ++fo) {
        #pragma unroll
        for (int r = 0; r < 4; ++r) {
            const int o = o0w + fo*16 + sub*4 + r;
            const float hv = h[b*256 + o];
            float* op = out + ((size_t)(b*256 + o))*T_LEN + t0;
            #pragma unroll
            for (int ft = 0; ft < 4; ++ft)
                op[ft*16 + li] = acc[fo][ft][r] + hv;
        }
    }
}

// ---------------------------------------------------------------------------
// Kernel D1: finalize GN-4 stats -> A2, D2.
// ---------------------------------------------------------------------------
__global__ __launch_bounds__(128) void kD1_finalize(
    const float* __restrict__ s2p, const float* __restrict__ q2p,
    const float* __restrict__ ln2_w, const float* __restrict__ ln2_b,
    float* __restrict__ A2, float* __restrict__ D2)
{
    const int b = blockIdx.x;
    const int o = threadIdx.x;
    float s = 0.f, qq = 0.f;
    for (int tb = 0; tb < NTB; ++tb) {
        s  += s2p[((size_t)b*NTB + tb)*128 + o];
        qq += q2p[((size_t)b*NTB + tb)*128 + o];
    }
    float S = s, Q = qq;
    #pragma unroll
    for (int off = 32; off; off >>= 1) {
        S += __shfl_down(S, off, 64);
        Q += __shfl_down(Q, off, 64);
    }
    __shared__ float rS[2], rQ[2];
    if ((o & 63) == 0) { rS[o >> 6] = S; rQ[o >> 6] = Q; }
    __syncthreads();
    const float N2inv = 1.f / (128.f * 16000.f);
    const float mu  = (rS[0] + rS[1]) * N2inv;
    const float var = (rQ[0] + rQ[1]) * N2inv - mu * mu;
    const float r = rsqrtf(var + EPSV);
    A2[b*128 + o] = ln2_w[o] * r;
    D2[b*128 + o] = ln2_b[o] - mu * ln2_w[o] * r;
}

// ---------------------------------------------------------------------------
// Kernel D2: F = conv2 * diag(A2) * M  (bf16 hi/lo planes) ; h vector.
// ---------------------------------------------------------------------------
__global__ __launch_bounds__(256) void kD2_buildF(
    const float* __restrict__ M, const float* __restrict__ e,
    const float* __restrict__ A2, const float* __restrict__ D2,
    const float* __restrict__ conv2_w,
    ushort* __restrict__ Fh, ushort* __restrict__ Fl, float* __restrict__ h)
{
    const int b = blockIdx.y, pg = blockIdx.x;
    const int tid = threadIdx.x;
    __shared__ float Qs[32][128];
    #pragma unroll
    for (int k = 0; k < 16; ++k) {
        const int idx = tid + k*256;
        const int p = idx >> 7, o = idx & 127;
        Qs[p][o] = conv2_w[(pg*32 + p)*128 + o] * A2[b*128 + o];
    }
    __syncthreads();
    float acc[32];
    #pragma unroll
    for (int p = 0; p < 32; ++p) acc[p] = 0.f;
    for (int o = 0; o < 128; ++o) {
        const float mv = M[((size_t)b*128 + o)*256 + tid];
        #pragma unroll
        for (int p = 0; p < 32; ++p) acc[p] = fmaf(Qs[p][o], mv, acc[p]);
    }
    #pragma unroll
    for (int p = 0; p < 32; ++p) {
        const size_t idx = ((size_t)b*256 + pg*32 + p)*256 + tid;
        ushort hh, ll; bfsplit(acc[p], hh, ll);
        Fh[idx] = hh; Fl[idx] = ll;
    }
    if (tid < 32) {
        const int p = pg*32 + tid;
        float hv = 0.f;
        for (int o = 0; o < 128; ++o)
            hv += Qs[tid][o] * e[b*128 + o] + conv2_w[p*128 + o] * D2[b*128 + o];
        h[b*256 + p] = hv;
    }
}

// ---------------------------------------------------------------------------
// Fallback (round-2) kC/kE with in-kernel split+transpose via LDS.
// ---------------------------------------------------------------------------
__global__ __launch_bounds__(256, 2) void kC_lds(
    const float* __restrict__ x,
    const ushort* __restrict__ Mh, const ushort* __restrict__ Ml,
    const float* __restrict__ e,
    float* __restrict__ s2p, float* __restrict__ q2p)
{
    const int tb = blockIdx.x;
    const int b  = blockIdx.y;
    const int tid  = threadIdx.x;
    const int lane = tid & 63;
    const int wid  = tid >> 6;
    const int o0w = (wid >> 1) * 64;
    const int t0w = (wid & 1) * 64;
    const int sub = lane >> 4;
    const int li  = lane & 15;
    const int t0  = tb * 128;

    __shared__ uint4 XsH[2][128*8];
    __shared__ uint4 XsL[2][128*8];
    __shared__ float sSp[2][128], sQp[2][128];

    f32x4 acc[4][4];
    #pragma unroll
    for (int i = 0; i < 4; ++i)
        #pragma unroll
        for (int j = 0; j < 4; ++j) acc[i][j] = (f32x4){0.f, 0.f, 0.f, 0.f};

    const int g  = tid >> 5;
    const int t4 = tid & 31;

    float4 xr[8];
    #pragma unroll
    for (int k = 0; k < 8; ++k)
        xr[k] = *(const float4*)(x + ((size_t)(b*256 + g*8 + k))*T_LEN + t0 + t4*4);

    for (int ck = 0; ck < 4; ++ck) {
        const int buf = ck & 1;
        #pragma unroll
        for (int i = 0; i < 4; ++i) {
            const int t = t4*4 + i;
            uint hh[4], ll[4];
            #pragma unroll
            for (int d = 0; d < 4; ++d) {
                ushort ha, la, hb, lb;
                bfsplit(f4c(xr[2*d],   i), ha, la);
                bfsplit(f4c(xr[2*d+1], i), hb, lb);
                hh[d] = (uint)ha | ((uint)hb << 16);
                ll[d] = (uint)la | ((uint)lb << 16);
            }
            const int idx = t*8 + swz(g, t);
            XsH[buf][idx] = (uint4){hh[0], hh[1], hh[2], hh[3]};
            XsL[buf][idx] = (uint4){ll[0], ll[1], ll[2], ll[3]};
        }
        if (ck < 3) {
            #pragma unroll
            for (int k = 0; k < 8; ++k)
                xr[k] = *(const float4*)(x + ((size_t)(b*256 + (ck+1)*64 + g*8 + k))*T_LEN + t0 + t4*4);
        }
        __syncthreads();
        #pragma unroll
        for (int ks = 0; ks < 2; ++ks) {
            const int kkg = ck*64 + ks*32 + 8*sub;
            const int uo  = ks*4 + sub;
            bf16x8 bh[4], bl[4];
            #pragma unroll
            for (int ft = 0; ft < 4; ++ft) {
                const int t = t0w + ft*16 + li;
                const int idx = t*8 + swz(uo, t);
                bh[ft] = *(const bf16x8*)&XsH[buf][idx];
                bl[ft] = *(const bf16x8*)&XsL[buf][idx];
            }
            #pragma unroll
            for (int fo = 0; fo < 4; ++fo) {
                const int o = o0w + fo*16 + li;
                const size_t base = ((size_t)(b*128 + o))*256 + kkg;
                bf16x8 ah = *(const bf16x8*)(Mh + base);
                bf16x8 al = *(const bf16x8*)(Ml + base);
                #pragma unroll
                for (int ft = 0; ft < 4; ++ft) {
                    acc[fo][ft] = __builtin_amdgcn_mfma_f32_16x16x32_bf16(ah, bh[ft], acc[fo][ft], 0, 0, 0);
                    acc[fo][ft] = __builtin_amdgcn_mfma_f32_16x16x32_bf16(al, bh[ft], acc[fo][ft], 0, 0, 0);
                    acc[fo][ft] = __builtin_amdgcn_mfma_f32_16x16x32_bf16(ah, bl[ft], acc[fo][ft], 0, 0, 0);
                }
            }
        }
        __syncthreads();
    }

    #pragma unroll
    for (int fo = 0; fo < 4; ++fo) {
        #pragma unroll
        for (int r = 0; r < 4; ++r) {
            const int o = o0w + fo*16 + sub*4 + r;
            const float ev = e[b*128 + o];
            float sv = 0.f, qv = 0.f;
            #pragma unroll
            for (int ft = 0; ft < 4; ++ft) {
                const float z = acc[fo][ft][r] + ev;
                sv += z; qv += z*z;
            }
            #pragma unroll
            for (int m = 1; m <= 8; m <<= 1) {
                sv += __shfl_xor(sv, m, 64);
                qv += __shfl_xor(qv, m, 64);
            }
            if (li == 0) { sSp[wid & 1][o] = sv; sQp[wid & 1][o] = qv; }
        }
    }
    __syncthreads();
    if (tid < 128) {
        s2p[((size_t)b*NTB + tb)*128 + tid] = sSp[0][tid] + sSp[1][tid];
        q2p[((size_t)b*NTB + tb)*128 + tid] = sQp[0][tid] + sQp[1][tid];
    }
}

__global__ __launch_bounds__(256, 2) void kE_lds(
    const float* __restrict__ x,
    const ushort* __restrict__ Fh, const ushort* __restrict__ Fl,
    const float* __restrict__ h,
    float* __restrict__ out)
{
    const int tb = blockIdx.x;
    const int b  = blockIdx.y;
    const int tid  = threadIdx.x;
    const int lane = tid & 63;
    const int wid  = tid >> 6;
    const int o0w = wid * 64;
    const int sub = lane >> 4;
    const int li  = lane & 15;
    const int t0  = tb * 64;

    __shared__ uint4 XsH[2][64*8];
    __shared__ uint4 XsL[2][64*8];

    f32x4 acc[4][4];
    #pragma unroll
    for (int i = 0; i < 4; ++i)
        #pragma unroll
        for (int j = 0; j < 4; ++j) acc[i][j] = (f32x4){0.f, 0.f, 0.f, 0.f};

    const int g  = tid >> 4;
    const int t4 = tid & 15;
    const int u  = g >> 1;

    float4 xr[4];
    #pragma unroll
    for (int k = 0; k < 4; ++k)
        xr[k] = *(const float4*)(x + ((size_t)(b*256 + g*4 + k))*T_LEN + t0 + t4*4);

    for (int ck = 0; ck < 4; ++ck) {
        const int buf = ck & 1;
        #pragma unroll
        for (int i = 0; i < 4; ++i) {
            const int t = t4*4 + i;
            ushort h0, l0, h1, l1, h2, l2, h3, l3;
            bfsplit(f4c(xr[0], i), h0, l0);
            bfsplit(f4c(xr[1], i), h1, l1);
            bfsplit(f4c(xr[2], i), h2, l2);
            bfsplit(f4c(xr[3], i), h3, l3);
            uint hA = (uint)h0 | ((uint)h1 << 16);
            uint hB = (uint)h2 | ((uint)h3 << 16);
            uint lA = (uint)l0 | ((uint)l1 << 16);
            uint lB = (uint)l2 | ((uint)l3 << 16);
            uint phA = (uint)__shfl_xor((int)hA, 16, 64);
            uint phB = (uint)__shfl_xor((int)hB, 16, 64);
            uint plA = (uint)__shfl_xor((int)lA, 16, 64);
            uint plB = (uint)__shfl_xor((int)lB, 16, 64);
            const int idx = t*8 + swz(u, t);
            if ((g & 1) == 0) XsH[buf][idx] = (uint4){hA, hB, phA, phB};
            else              XsL[buf][idx] = (uint4){plA, plB, lA, lB};
        }
        if (ck < 3) {
            #pragma unroll
            for (int k = 0; k < 4; ++k)
                xr[k] = *(const float4*)(x + ((size_t)(b*256 + (ck+1)*64 + g*4 + k))*T_LEN + t0 + t4*4);
        }
        __syncthreads();
        #pragma unroll
        for (int ks = 0; ks < 2; ++ks) {
            const int kkg = ck*64 + ks*32 + 8*sub;
            const int uo  = ks*4 + sub;
            bf16x8 bh[4], bl[4];
            #pragma unroll
            for (int ft = 0; ft < 4; ++ft) {
                const int t = ft*16 + li;
                const int idx = t*8 + swz(uo, t);
                bh[ft] = *(const bf16x8*)&XsH[buf][idx];
                bl[ft] = *(const bf16x8*)&XsL[buf][idx];
            }
            #pragma unroll
            for (int fo = 0; fo < 4; ++fo) {
                const int o = o0w + fo*16 + li;
                const size_t base = ((size_t)(b*256 + o))*256 + kkg;
                bf16x8 ah = *(const bf16x8*)(Fh + base);
                bf16x8 al = *(const bf16x8*)(Fl + base);
                #pragma unroll
                for (int ft = 0; ft < 4; ++ft) {
                    acc[fo][ft] = __builtin_amdgcn_mfma_f32_16x16x32_bf16(ah, bh[ft], acc[fo][ft], 0, 0, 0);
                    acc[fo][ft] = __builtin_amdgcn_mfma_f32_16x16x32_bf16(al, bh[ft], acc[fo][ft], 0, 0, 0);
                    acc[fo][ft] = __builtin_amdgcn_mfma_f32_16x16x32_bf16(ah, bl[ft], acc[fo][ft], 0, 0, 0);
                }
            }
        }
        __syncthreads();
    }

    #pragma unroll
    for (int fo = 0; fo < 4; ++fo) {
        #pragma unroll
        for (int r = 0; r < 4; ++r) {
            const int o = o0w + fo*16 + sub*4 + r;
            const float hv = h[b*256 + o];
            float* op = out + ((size_t)(b*256 + o))*T_LEN + t0;
            #pragma unroll
            for (int ft = 0; ft < 4; ++ft)
                op[ft*16 + li] = acc[fo][ft][r] + hv;
        }
    }
}

// ---------------------------------------------------------------------------
extern "C" void kernel_launch(void* const* d_in, const int* in_sizes, int n_in,
                              void* d_out, int out_size, void* d_ws, size_t ws_size,
                              hipStream_t stream)
{
    const float* x       = (const float*)d_in[0];
    const float* cue     = (const float*)d_in[1];
    const float* gn_a_w  = (const float*)d_in[2];
    const float* gn_a_b  = (const float*)d_in[3];
    const float* gn_n_w  = (const float*)d_in[4];
    const float* gn_n_b  = (const float*)d_in[5];
    const float* f1g_w   = (const float*)d_in[6];
    const float* f1g_b   = (const float*)d_in[7];
    const float* f1b_w   = (const float*)d_in[8];
    const float* f1b_b   = (const float*)d_in[9];
    const float* ln1_w   = (const float*)d_in[10];
    const float* ln1_b   = (const float*)d_in[11];
    const float* conv1_w = (const float*)d_in[12];
    const float* cds_w   = (const float*)d_in[13];
    const float* f2g_w   = (const float*)d_in[14];
    const float* f2g_b   = (const float*)d_in[15];
    const float* f2b_w   = (const float*)d_in[16];
    const float* f2b_b   = (const float*)d_in[17];
    const float* ln2_w   = (const float*)d_in[18];
    const float* ln2_b   = (const float*)d_in[19];
    const float* conv2_w = (const float*)d_in[20];
    float* out = (float*)d_out;

    float* ws  = (float*)d_ws;
    float* s    = ws;                   // 4096
    float* q    = ws + 4096;            // 4096
    float* M    = ws + 8192;            // 524288
    float* e    = ws + 532480;          // 2048
    float* A2   = ws + 534528;          // 2048
    float* D2   = ws + 536576;          // 2048
    float* h    = ws + 538624;          // 4096
    float* s2p  = ws + 542720;          // 256000
    float* q2p  = ws + 798720;          // 256000
    ushort* Mh  = (ushort*)(ws + 1054720);  // 16*128*256 ush (262144 f)
    ushort* Ml  = (ushort*)(ws + 1316864);
    ushort* Fh  = (ushort*)(ws + 1579008);  // 16*256*256 ush (524288 f)
    ushort* Fl  = (ushort*)(ws + 2103296);  // subtotal 2627584 f
    float* sp   = ws + 2627584;             // 16*250*256 = 1024000
    float* qp   = ws + 3651584;             // 1024000
    ushort* Xth = (ushort*)(ws + 4675584);  // 16*16000*256 ush (32768000 f)
    ushort* Xtl = (ushort*)(ws + 37443584); // total 70211584 f = 280.8 MB

    const size_t need = (size_t)70211584 * 4;
    const bool big = ws_size >= need;

    if (big) {
        kP1_split<<<dim3(NTP, NB), 256, 0, stream>>>(x, Xth, Xtl, sp, qp);

        kB_compose<<<NB, 256, 0, stream>>>(sp, qp, NTP, cue,
            gn_a_w, gn_a_b, gn_n_w, gn_n_b,
            f1g_w, f1g_b, f1b_w, f1b_b, ln1_w, ln1_b,
            conv1_w, cds_w, f2g_w, f2g_b, f2b_w, f2b_b,
            M, Mh, Ml, e);

        kC_direct<<<dim3(NTB, NB), 256, 0, stream>>>(Xth, Xtl, Mh, Ml, e, s2p, q2p);

        kD1_finalize<<<NB, 128, 0, stream>>>(s2p, q2p, ln2_w, ln2_b, A2, D2);

        kD2_buildF<<<dim3(8, NB), 256, 0, stream>>>(M, e, A2, D2, conv2_w, Fh, Fl, h);

        kE_direct<<<dim3(NTE, NB), 256, 0, stream>>>(Xth, Xtl, Fh, Fl, h, out);
    } else {
        kA_rowstats<<<NB*256, 256, 0, stream>>>(x, s, q);

        kB_compose<<<NB, 256, 0, stream>>>(s, q, 0, cue,
            gn_a_w, gn_a_b, gn_n_w, gn_n_b,
            f1g_w, f1g_b, f1b_w, f1b_b, ln1_w, ln1_b,
            conv1_w, cds_w, f2g_w, f2g_b, f2b_w, f2b_b,
            M, Mh, Ml, e);

        kC_lds<<<dim3(NTB, NB), 256, 0, stream>>>(x, Mh, Ml, e, s2p, q2p);

        kD1_finalize<<<NB, 128, 0, stream>>>(s2p, q2p, ln2_w, ln2_b, A2, D2);

        kD2_buildF<<<dim3(8, NB), 256, 0, stream>>>(M, e, A2, D2, conv2_w, Fh, Fl, h);

        kE_lds<<<dim3(NTE, NB), 256, 0, stream>>>(x, Fh, Fl, h, out);
    }
}

// Round 4
// 493.215 us; speedup vs baseline: 1.5837x; 1.5837x over previous
//
#include <hip/hip_runtime.h>
#include <hip/hip_bf16.h>
#include <hip/hip_fp16.h>

#define T_LEN   16000
#define NB      16
#define NTT     250         // T_LEN / 64 : plane chunks & kP1/kE tiles
#define NTB     125         // T_LEN / 128: kC tiles
#define EPSV    1e-8f

typedef _Float16 f16x8 __attribute__((ext_vector_type(8)));
typedef float    f32x4 __attribute__((ext_vector_type(4)));

__device__ __forceinline__ ushort f2h(float f) {
    _Float16 h = (_Float16)f;
    return *(ushort*)&h;
}
__device__ __forceinline__ float f4c(const float4& v, int i) {
    return i == 0 ? v.x : i == 1 ? v.y : i == 2 ? v.z : v.w;
}
// async global->LDS, 16B per lane; LDS dest = wave-uniform base + lane*16
__device__ __forceinline__ void gld16(const ushort* g, ushort* l) {
    __builtin_amdgcn_global_load_lds(
        (const __attribute__((address_space(1))) uint*)g,
        (__attribute__((address_space(3))) uint*)l, 16, 0, 0);
}

// ---------------------------------------------------------------------------
// Plane layout: Xp[b][tt(250)][kc(4)] = 8KB chunk of 64t x 64k fp16.
// Within chunk: 16B unit (t, u in [0,8)) stored at ushort off (t*8 + (u^(t&7)))*8.
// The XOR makes ds_read_b128 fragments bank-balanced; DMA stays linear.
// ---------------------------------------------------------------------------

// ---------------------------------------------------------------------------
// Pass 1: read X once -> per-(b,c) partial s,q over 64-t tile + fp16 plane.
// grid (250,16) x 256.
// ---------------------------------------------------------------------------
__global__ __launch_bounds__(256) void kP1_split(
    const float* __restrict__ x, ushort* __restrict__ Xp,
    float* __restrict__ sp, float* __restrict__ qp)
{
    const int tt = blockIdx.x, b = blockIdx.y;
    const int t0 = tt * 64;
    const int tid = threadIdx.x;
    const int j = tid & 15, cg = tid >> 4;
    __shared__ __align__(16) ushort Hs[64][264];   // row stride 528B -> 4-ish way

    #pragma unroll
    for (int p = 0; p < 4; ++p) {
        #pragma unroll
        for (int k = 0; k < 4; ++k) {
            const int c = k*64 + p*16 + cg;
            const float4 v = *(const float4*)(x + ((size_t)(b*256 + c))*T_LEN + t0 + j*4);
            float s4 = 0.f, q4 = 0.f;
            #pragma unroll
            for (int i = 0; i < 4; ++i) {
                const float f = f4c(v, i);
                s4 += f; q4 += f*f;
                Hs[j*4 + i][c] = f2h(f);
            }
            #pragma unroll
            for (int m = 1; m <= 8; m <<= 1) {
                s4 += __shfl_xor(s4, m, 16);
                q4 += __shfl_xor(q4, m, 16);
            }
            if (j == 0) {
                sp[((size_t)b*NTT + tt)*256 + c] = s4;
                qp[((size_t)b*NTT + tt)*256 + c] = q4;
            }
        }
    }
    __syncthreads();
    // write 4 chunks (kc=0..3) = 2048 16B-units, dst-linear for coalescing
    ushort* dst = Xp + ((size_t)(b*NTT + tt)*4)*4096;
    #pragma unroll
    for (int k = 0; k < 8; ++k) {
        const int d  = tid + k*256;          // unit idx 0..2047
        const int kc = d >> 9, r = d & 511;
        const int t  = r >> 3, us = r & 7;
        const int u  = us ^ (t & 7);         // logical k-unit stored at slot us
        *(uint4*)(dst + (size_t)d*8) = *(const uint4*)&Hs[t][kc*64 + u*8];
    }
}

// ---------------------------------------------------------------------------
__device__ __forceinline__ float blockSum256(float v, float* red)
{
    #pragma unroll
    for (int off = 32; off; off >>= 1) v += __shfl_down(v, off, 64);
    __syncthreads();
    if ((threadIdx.x & 63) == 0) red[threadIdx.x >> 6] = v;
    __syncthreads();
    return red[0] + red[1] + red[2] + red[3];
}

// ---------------------------------------------------------------------------
// Kernel B: analytic affine composition -> M (fp32 + fp16), e.
// ---------------------------------------------------------------------------
__global__ __launch_bounds__(256) void kB_compose(
    const float* __restrict__ sArr,   const float* __restrict__ qArr, int ntiles,
    const float* __restrict__ cue,
    const float* __restrict__ gn_a_w, const float* __restrict__ gn_a_b,
    const float* __restrict__ gn_n_w, const float* __restrict__ gn_n_b,
    const float* __restrict__ f1g_w,  const float* __restrict__ f1g_b,
    const float* __restrict__ f1b_w,  const float* __restrict__ f1b_b,
    const float* __restrict__ ln1_w,  const float* __restrict__ ln1_b,
    const float* __restrict__ conv1_w,const float* __restrict__ cds_w,
    const float* __restrict__ f2g_w,  const float* __restrict__ f2g_b,
    const float* __restrict__ f2b_w,  const float* __restrict__ f2b_b,
    float* __restrict__ Mout, ushort* __restrict__ Msf,
    float* __restrict__ eout)
{
    const int b = blockIdx.x;
    const int c = threadIdx.x;           // 0..255
    __shared__ float red[4];
    __shared__ float sh_cue[512];
    __shared__ float sh_a[256], sh_d[256], sh_cue2[256], sh_g2[128];

    sh_cue[c]       = cue[b*512 + c];
    sh_cue[256 + c] = cue[b*512 + 256 + c];
    float sc = 0.f, qc = 0.f;
    for (int i = 0; i < ntiles; ++i) {
        sc += sArr[((size_t)b*ntiles + i)*256 + c];
        qc += qArr[((size_t)b*ntiles + i)*256 + c];
    }
    __syncthreads();

    const float Ninv = 1.f / (256.f * 16000.f);
    const float Tf = 16000.f;

    float S  = blockSum256(sc, red);
    float Q  = blockSum256(qc, red);
    float mu1 = S * Ninv;
    float var1 = Q * Ninv - mu1 * mu1;
    float r1 = rsqrtf(var1 + EPSV);
    float a1 = gn_a_w[c] * r1;
    float d1 = gn_a_b[c] - mu1 * r1 * gn_a_w[c];

    float S2 = blockSum256(a1*sc + Tf*d1, red);
    float Q2 = blockSum256(a1*a1*qc + 2.f*a1*d1*sc + Tf*d1*d1, red);
    float mu2 = S2 * Ninv;
    float var2 = Q2 * Ninv - mu2 * mu2;
    float r2 = rsqrtf(var2 + EPSV);
    float wn = gn_n_w[c];
    float a2 = wn * r2 * a1;
    float d2 = wn * r2 * (d1 - mu2) + gn_n_b[c];

    float g1 = f1g_b[c], b1 = f1b_b[c];
    for (int k = 0; k < 512; ++k) {
        const float cv = sh_cue[k];
        g1 = fmaf(cv, f1g_w[c*512 + k], g1);
        b1 = fmaf(cv, f1b_w[c*512 + k], b1);
    }
    g1 = fmaxf(g1, 0.f) + 1.f;
    b1 = fmaxf(b1, 0.f);
    float a3 = g1 * a2;
    float d3 = g1 * d2 + b1;

    float S3 = blockSum256(a3*sc + Tf*d3, red);
    float Q3 = blockSum256(a3*a3*qc + 2.f*a3*d3*sc + Tf*d3*d3, red);
    float mu3 = S3 * Ninv;
    float var3 = Q3 * Ninv - mu3 * mu3;
    float r3 = rsqrtf(var3 + EPSV);
    float w1 = ln1_w[c];
    float a4 = w1 * r3 * a3;
    float d4 = w1 * r3 * (d3 - mu3) + ln1_b[c];
    sh_a[c] = a4;
    sh_d[c] = d4;

    float c2 = 0.f;
    for (int k = 0; k < 512; ++k) c2 = fmaf(sh_cue[k], cds_w[c*512 + k], c2);
    sh_cue2[c] = fmaxf(c2, 0.f);
    __syncthreads();

    if (c < 128) {
        float g2 = f2g_b[c], b2 = f2b_b[c];
        for (int k = 0; k < 256; ++k) {
            const float cv = sh_cue2[k];
            g2 = fmaf(cv, f2g_w[c*256 + k], g2);
            b2 = fmaf(cv, f2b_w[c*256 + k], b2);
        }
        g2 = fmaxf(g2, 0.f) + 1.f;
        b2 = fmaxf(b2, 0.f);
        float u = 0.f;
        for (int k = 0; k < 256; ++k) u = fmaf(conv1_w[c*256 + k], sh_d[k], u);
        eout[b*128 + c] = g2 * u + b2;
        sh_g2[c] = g2;
    }
    __syncthreads();

    for (int o = 0; o < 128; ++o) {
        const float m = sh_g2[o] * conv1_w[o*256 + c] * sh_a[c];
        const size_t idx = ((size_t)b*128 + o)*256 + c;
        Mout[idx] = m;
        Msf[idx] = f2h(m);
    }
}

// ---------------------------------------------------------------------------
// Kernel C: stats GEMM z2 = M x + e.  Block 128o x 128t, 4 waves (2o x 2t).
// B staged via global_load_lds dbuf (2 chunks/buf); A (Msf) direct from L2.
// ---------------------------------------------------------------------------
__global__ __launch_bounds__(256) void kC_gemm(
    const ushort* __restrict__ Xp, const ushort* __restrict__ Msf,
    const float* __restrict__ e,
    float* __restrict__ s2p, float* __restrict__ q2p)
{
    const int tb = blockIdx.x, b = blockIdx.y;
    const int tid = threadIdx.x, lane = tid & 63, w = tid >> 6;
    const int wo = w >> 1, wt = w & 1;
    const int sub = lane >> 4, li = lane & 15;
    const int o0 = wo * 64;
    __shared__ __align__(16) ushort Bs[2][8192];   // 2 x 16KB
    __shared__ float sSp[2][128], sQp[2][128];

    const ushort* src = Xp + ((size_t)(b*NTT + 2*tb)*4)*4096;  // +ch*16384 for tt half
    const ushort* mp  = Msf + (size_t)b*128*256;

    f32x4 acc[4][4];
    #pragma unroll
    for (int i = 0; i < 4; ++i)
        #pragma unroll
        for (int jx = 0; jx < 4; ++jx) acc[i][jx] = (f32x4){0.f,0.f,0.f,0.f};

    #pragma unroll
    for (int jj = 0; jj < 4; ++jj) {
        const int m = w*4 + jj;
        const int ch = m >> 3, off = (m & 7)*512;
        gld16(src + (size_t)ch*16384 + off + lane*8, &Bs[0][ch*4096 + off]);
    }
    __syncthreads();
    for (int kc = 0; kc < 4; ++kc) {
        const int buf = kc & 1;
        if (kc < 3) {
            #pragma unroll
            for (int jj = 0; jj < 4; ++jj) {
                const int m = w*4 + jj;
                const int ch = m >> 3, off = (m & 7)*512;
                gld16(src + (size_t)ch*16384 + (kc+1)*4096 + off + lane*8,
                      &Bs[buf^1][ch*4096 + off]);
            }
        }
        f16x8 bfr[4][2];
        #pragma unroll
        for (int ft = 0; ft < 4; ++ft) {
            const int tl = ft*16 + li;
            #pragma unroll
            for (int ks = 0; ks < 2; ++ks) {
                const int u = (4*ks + sub) ^ (tl & 7);
                bfr[ft][ks] = *(const f16x8*)&Bs[buf][wt*4096 + tl*64 + u*8];
            }
        }
        #pragma unroll
        for (int ks = 0; ks < 2; ++ks) {
            #pragma unroll
            for (int fo = 0; fo < 4; ++fo) {
                const f16x8 a = *(const f16x8*)(mp + (size_t)(o0 + fo*16 + li)*256 + kc*64 + ks*32 + 8*sub);
                #pragma unroll
                for (int ft = 0; ft < 4; ++ft)
                    acc[fo][ft] = __builtin_amdgcn_mfma_f32_16x16x32_f16(a, bfr[ft][ks], acc[fo][ft], 0, 0, 0);
            }
        }
        __syncthreads();
    }

    // stats: z = acc + e[o]; per-o sum/sumsq over this 128-t tile
    #pragma unroll
    for (int fo = 0; fo < 4; ++fo) {
        #pragma unroll
        for (int r = 0; r < 4; ++r) {
            const int o = o0 + fo*16 + sub*4 + r;
            const float ev = e[b*128 + o];
            float sv = 0.f, qv = 0.f;
            #pragma unroll
            for (int ft = 0; ft < 4; ++ft) {
                const float z = acc[fo][ft][r] + ev;
                sv += z; qv += z*z;
            }
            #pragma unroll
            for (int m = 1; m <= 8; m <<= 1) {
                sv += __shfl_xor(sv, m, 64);
                qv += __shfl_xor(qv, m, 64);
            }
            if (li == 0) { sSp[wt][o] = sv; sQp[wt][o] = qv; }
        }
    }
    __syncthreads();
    if (tid < 128) {
        s2p[((size_t)b*NTB + tb)*128 + tid] = sSp[0][tid] + sSp[1][tid];
        q2p[((size_t)b*NTB + tb)*128 + tid] = sQp[0][tid] + sQp[1][tid];
    }
}

// ---------------------------------------------------------------------------
// Kernel E: out = F x + h.  Block 256o x 64t, 4 waves = 4 o-strips.
// B (one 8KB chunk) staged via global_load_lds dbuf; A (Fsf) direct from L2.
// ---------------------------------------------------------------------------
__global__ __launch_bounds__(256) void kE_gemm(
    const ushort* __restrict__ Xp, const ushort* __restrict__ Fsf,
    const float* __restrict__ h, float* __restrict__ out)
{
    const int tt = blockIdx.x, b = blockIdx.y;
    const int tid = threadIdx.x, lane = tid & 63, w = tid >> 6;
    const int sub = lane >> 4, li = lane & 15;
    const int o0 = w * 64, t0 = tt * 64;
    __shared__ __align__(16) ushort Bs[2][4096];   // 2 x 8KB

    const ushort* src = Xp + ((size_t)(b*NTT + tt)*4)*4096;
    const ushort* fp  = Fsf + (size_t)b*65536;

    f32x4 acc[4][4];
    #pragma unroll
    for (int i = 0; i < 4; ++i)
        #pragma unroll
        for (int jx = 0; jx < 4; ++jx) acc[i][jx] = (f32x4){0.f,0.f,0.f,0.f};

    #pragma unroll
    for (int jj = 0; jj < 2; ++jj) {
        const int m = w*2 + jj;
        gld16(src + m*512 + lane*8, &Bs[0][m*512]);
    }
    __syncthreads();
    for (int kc = 0; kc < 4; ++kc) {
        const int buf = kc & 1;
        if (kc < 3) {
            #pragma unroll
            for (int jj = 0; jj < 2; ++jj) {
                const int m = w*2 + jj;
                gld16(src + (kc+1)*4096 + m*512 + lane*8, &Bs[buf^1][m*512]);
            }
        }
        f16x8 bfr[4][2];
        #pragma unroll
        for (int ft = 0; ft < 4; ++ft) {
            const int t = ft*16 + li;
            #pragma unroll
            for (int ks = 0; ks < 2; ++ks) {
                const int u = (4*ks + sub) ^ (t & 7);
                bfr[ft][ks] = *(const f16x8*)&Bs[buf][t*64 + u*8];
            }
        }
        #pragma unroll
        for (int ks = 0; ks < 2; ++ks) {
            #pragma unroll
            for (int fo = 0; fo < 4; ++fo) {
                const f16x8 a = *(const f16x8*)(fp + (size_t)(o0 + fo*16 + li)*256 + kc*64 + ks*32 + 8*sub);
                #pragma unroll
                for (int ft = 0; ft < 4; ++ft)
                    acc[fo][ft] = __builtin_amdgcn_mfma_f32_16x16x32_f16(a, bfr[ft][ks], acc[fo][ft], 0, 0, 0);
            }
        }
        __syncthreads();
    }

    #pragma unroll
    for (int fo = 0; fo < 4; ++fo) {
        #pragma unroll
        for (int r = 0; r < 4; ++r) {
            const int o = o0 + fo*16 + sub*4 + r;
            const float hv = h[b*256 + o];
            float* op = out + ((size_t)(b*256 + o))*T_LEN + t0;
            #pragma unroll
            for (int ft = 0; ft < 4; ++ft)
                op[ft*16 + li] = acc[fo][ft][r] + hv;
        }
    }
}

// ---------------------------------------------------------------------------
// Kernel D1: finalize GN-4 stats -> A2, D2.
// ---------------------------------------------------------------------------
__global__ __launch_bounds__(128) void kD1_finalize(
    const float* __restrict__ s2p, const float* __restrict__ q2p,
    const float* __restrict__ ln2_w, const float* __restrict__ ln2_b,
    float* __restrict__ A2, float* __restrict__ D2)
{
    const int b = blockIdx.x;
    const int o = threadIdx.x;
    float s = 0.f, qq = 0.f;
    for (int tb = 0; tb < NTB; ++tb) {
        s  += s2p[((size_t)b*NTB + tb)*128 + o];
        qq += q2p[((size_t)b*NTB + tb)*128 + o];
    }
    float S = s, Q = qq;
    #pragma unroll
    for (int off = 32; off; off >>= 1) {
        S += __shfl_down(S, off, 64);
        Q += __shfl_down(Q, off, 64);
    }
    __shared__ float rS[2], rQ[2];
    if ((o & 63) == 0) { rS[o >> 6] = S; rQ[o >> 6] = Q; }
    __syncthreads();
    const float N2inv = 1.f / (128.f * 16000.f);
    const float mu  = (rS[0] + rS[1]) * N2inv;
    const float var = (rQ[0] + rQ[1]) * N2inv - mu * mu;
    const float r = rsqrtf(var + EPSV);
    A2[b*128 + o] = ln2_w[o] * r;
    D2[b*128 + o] = ln2_b[o] - mu * ln2_w[o] * r;
}

// ---------------------------------------------------------------------------
// Kernel D2: F = conv2 * diag(A2) * M (fp16) ; h vector.
// ---------------------------------------------------------------------------
__global__ __launch_bounds__(256) void kD2_buildF(
    const float* __restrict__ M, const float* __restrict__ e,
    const float* __restrict__ A2, const float* __restrict__ D2,
    const float* __restrict__ conv2_w,
    ushort* __restrict__ Fsf, float* __restrict__ h)
{
    const int b = blockIdx.y, pg = blockIdx.x;
    const int tid = threadIdx.x;
    __shared__ float Qs[32][128];
    #pragma unroll
    for (int k = 0; k < 16; ++k) {
        const int idx = tid + k*256;
        const int p = idx >> 7, o = idx & 127;
        Qs[p][o] = conv2_w[(pg*32 + p)*128 + o] * A2[b*128 + o];
    }
    __syncthreads();
    float acc[32];
    #pragma unroll
    for (int p = 0; p < 32; ++p) acc[p] = 0.f;
    for (int o = 0; o < 128; ++o) {
        const float mv = M[((size_t)b*128 + o)*256 + tid];
        #pragma unroll
        for (int p = 0; p < 32; ++p) acc[p] = fmaf(Qs[p][o], mv, acc[p]);
    }
    #pragma unroll
    for (int p = 0; p < 32; ++p) {
        const size_t idx = ((size_t)b*256 + pg*32 + p)*256 + tid;
        Fsf[idx] = f2h(acc[p]);
    }
    if (tid < 32) {
        const int p = pg*32 + tid;
        float hv = 0.f;
        for (int o = 0; o < 128; ++o)
            hv += Qs[tid][o] * e[b*128 + o] + conv2_w[p*128 + o] * D2[b*128 + o];
        h[b*256 + p] = hv;
    }
}

// ---------------------------------------------------------------------------
extern "C" void kernel_launch(void* const* d_in, const int* in_sizes, int n_in,
                              void* d_out, int out_size, void* d_ws, size_t ws_size,
                              hipStream_t stream)
{
    const float* x       = (const float*)d_in[0];
    const float* cue     = (const float*)d_in[1];
    const float* gn_a_w  = (const float*)d_in[2];
    const float* gn_a_b  = (const float*)d_in[3];
    const float* gn_n_w  = (const float*)d_in[4];
    const float* gn_n_b  = (const float*)d_in[5];
    const float* f1g_w   = (const float*)d_in[6];
    const float* f1g_b   = (const float*)d_in[7];
    const float* f1b_w   = (const float*)d_in[8];
    const float* f1b_b   = (const float*)d_in[9];
    const float* ln1_w   = (const float*)d_in[10];
    const float* ln1_b   = (const float*)d_in[11];
    const float* conv1_w = (const float*)d_in[12];
    const float* cds_w   = (const float*)d_in[13];
    const float* f2g_w   = (const float*)d_in[14];
    const float* f2g_b   = (const float*)d_in[15];
    const float* f2b_w   = (const float*)d_in[16];
    const float* f2b_b   = (const float*)d_in[17];
    const float* ln2_w   = (const float*)d_in[18];
    const float* ln2_b   = (const float*)d_in[19];
    const float* conv2_w = (const float*)d_in[20];
    float* out = (float*)d_out;

    float* ws = (float*)d_ws;
    float*  sp  = ws;                        // 16*250*256 = 1,024,000
    float*  qp  = ws + 1024000;              // 1,024,000
    float*  M   = ws + 2048000;              // 524,288
    float*  e   = ws + 2572288;              // 2,048
    float*  A2  = ws + 2574336;              // 2,048
    float*  D2  = ws + 2576384;              // 2,048
    float*  h   = ws + 2578432;              // 4,096
    float*  s2p = ws + 2582528;              // 256,000
    float*  q2p = ws + 2838528;              // 256,000
    ushort* Msf = (ushort*)(ws + 3094528);   // 524,288 ush
    ushort* Fsf = (ushort*)(ws + 3356672);   // 1,048,576 ush
    ushort* Xp  = (ushort*)(ws + 3880960);   // 65,536,000 ush (131 MB plane)
    // total = 36,648,960 floats ~= 146.6 MB (< ws_size, verified >= 281 MB in R3)

    kP1_split<<<dim3(NTT, NB), 256, 0, stream>>>(x, Xp, sp, qp);

    kB_compose<<<NB, 256, 0, stream>>>(sp, qp, NTT, cue,
        gn_a_w, gn_a_b, gn_n_w, gn_n_b,
        f1g_w, f1g_b, f1b_w, f1b_b, ln1_w, ln1_b,
        conv1_w, cds_w, f2g_w, f2g_b, f2b_w, f2b_b,
        M, Msf, e);

    kC_gemm<<<dim3(NTB, NB), 256, 0, stream>>>(Xp, Msf, e, s2p, q2p);

    kD1_finalize<<<NB, 128, 0, stream>>>(s2p, q2p, ln2_w, ln2_b, A2, D2);

    kD2_buildF<<<dim3(8, NB), 256, 0, stream>>>(M, e, A2, D2, conv2_w, Fsf, h);

    kE_gemm<<<dim3(NTT, NB), 256, 0, stream>>>(Xp, Fsf, h, out);
}

// Round 5
// 361.936 us; speedup vs baseline: 2.1582x; 1.3627x over previous
//
#include <hip/hip_runtime.h>
#include <hip/hip_bf16.h>
#include <hip/hip_fp16.h>

#define T_LEN   16000
#define NB      16
#define NTT     250         // T_LEN / 64 : plane chunks & kP1/kE tiles
#define NTB     125         // T_LEN / 128: kC tiles
#define EPSV    1e-8f

typedef _Float16 f16x8 __attribute__((ext_vector_type(8)));
typedef float    f32x4 __attribute__((ext_vector_type(4)));

__device__ __forceinline__ ushort f2h(float f) {
    _Float16 h = (_Float16)f;
    return *(ushort*)&h;
}
__device__ __forceinline__ float f4c(const float4& v, int i) {
    return i == 0 ? v.x : i == 1 ? v.y : i == 2 ? v.z : v.w;
}
__device__ __forceinline__ void gld16(const ushort* g, ushort* l) {
    __builtin_amdgcn_global_load_lds(
        (const __attribute__((address_space(1))) uint*)g,
        (__attribute__((address_space(3))) uint*)l, 16, 0, 0);
}
__device__ __forceinline__ float waveRed64(float v) {
    #pragma unroll
    for (int m = 1; m <= 32; m <<= 1) v += __shfl_xor(v, m, 64);
    return v;
}

// ---------------------------------------------------------------------------
// Pass 1: read X once -> per-(b,c) partial s,q over 64-t tile + fp16 plane.
// Plane: Xp[b][tt][kc] = 8KB chunk of 64t x 64k fp16; 16B unit (t,u) at
// (t*8 + (u^(t&7)))*8 ushorts. grid (250,16) x 256.
// ---------------------------------------------------------------------------
__global__ __launch_bounds__(256) void kP1_split(
    const float* __restrict__ x, ushort* __restrict__ Xp,
    float* __restrict__ sp, float* __restrict__ qp)
{
    const int tt = blockIdx.x, b = blockIdx.y;
    const int t0 = tt * 64;
    const int tid = threadIdx.x;
    const int j = tid & 15, cg = tid >> 4;
    __shared__ __align__(16) ushort Hs[64][264];

    #pragma unroll
    for (int p = 0; p < 4; ++p) {
        #pragma unroll
        for (int k = 0; k < 4; ++k) {
            const int c = k*64 + p*16 + cg;
            const float4 v = *(const float4*)(x + ((size_t)(b*256 + c))*T_LEN + t0 + j*4);
            float s4 = 0.f, q4 = 0.f;
            #pragma unroll
            for (int i = 0; i < 4; ++i) {
                const float f = f4c(v, i);
                s4 += f; q4 += f*f;
                Hs[j*4 + i][c] = f2h(f);
            }
            #pragma unroll
            for (int m = 1; m <= 8; m <<= 1) {
                s4 += __shfl_xor(s4, m, 16);
                q4 += __shfl_xor(q4, m, 16);
            }
            if (j == 0) {
                sp[((size_t)b*NTT + tt)*256 + c] = s4;
                qp[((size_t)b*NTT + tt)*256 + c] = q4;
            }
        }
    }
    __syncthreads();
    ushort* dst = Xp + ((size_t)(b*NTT + tt)*4)*4096;
    #pragma unroll
    for (int k = 0; k < 8; ++k) {
        const int d  = tid + k*256;
        const int kc = d >> 9, r = d & 511;
        const int t  = r >> 3, us = r & 7;
        const int u  = us ^ (t & 7);
        *(uint4*)(dst + (size_t)d*8) = *(const uint4*)&Hs[t][kc*64 + u*8];
    }
}

// ---------------------------------------------------------------------------
// kW1: per-channel cue GEMVs. G1=relu(f1g.cue+b)+1, B1=relu(f1b.cue+b),
// CUE2=relu(cds.cue).  grid 256 (c) x 256 thr; wave w -> batches 4w..4w+3.
// ---------------------------------------------------------------------------
__global__ __launch_bounds__(256) void kW1(
    const float* __restrict__ cue,
    const float* __restrict__ f1g_w, const float* __restrict__ f1g_b,
    const float* __restrict__ f1b_w, const float* __restrict__ f1b_b,
    const float* __restrict__ cds_w,
    float* __restrict__ G1, float* __restrict__ B1, float* __restrict__ CUE2)
{
    const int c = blockIdx.x;
    const int lane = threadIdx.x & 63, w = threadIdx.x >> 6;
    const float4 wg0 = *(const float4*)(f1g_w + c*512 + lane*8);
    const float4 wg1 = *(const float4*)(f1g_w + c*512 + lane*8 + 4);
    const float4 wb0 = *(const float4*)(f1b_w + c*512 + lane*8);
    const float4 wb1 = *(const float4*)(f1b_w + c*512 + lane*8 + 4);
    const float4 wc0 = *(const float4*)(cds_w + c*512 + lane*8);
    const float4 wc1 = *(const float4*)(cds_w + c*512 + lane*8 + 4);
    #pragma unroll
    for (int bb = 0; bb < 4; ++bb) {
        const int b = w*4 + bb;
        const float4 u0 = *(const float4*)(cue + b*512 + lane*8);
        const float4 u1 = *(const float4*)(cue + b*512 + lane*8 + 4);
        float g = 0.f, bt = 0.f, cv = 0.f;
        #pragma unroll
        for (int i = 0; i < 4; ++i) {
            g  = fmaf(f4c(u0,i), f4c(wg0,i), g);  g  = fmaf(f4c(u1,i), f4c(wg1,i), g);
            bt = fmaf(f4c(u0,i), f4c(wb0,i), bt); bt = fmaf(f4c(u1,i), f4c(wb1,i), bt);
            cv = fmaf(f4c(u0,i), f4c(wc0,i), cv); cv = fmaf(f4c(u1,i), f4c(wc1,i), cv);
        }
        g = waveRed64(g); bt = waveRed64(bt); cv = waveRed64(cv);
        if (lane == 0) {
            G1[b*256 + c]   = fmaxf(g + f1g_b[c], 0.f) + 1.f;
            B1[b*256 + c]   = fmaxf(bt + f1b_b[c], 0.f);
            CUE2[b*256 + c] = fmaxf(cv, 0.f);
        }
    }
}

// ---------------------------------------------------------------------------
// kW2: G2=relu(f2g.cue2+b)+1, B2=relu(f2b.cue2+b). grid 128 (o) x 256 thr.
// ---------------------------------------------------------------------------
__global__ __launch_bounds__(256) void kW2(
    const float* __restrict__ CUE2,
    const float* __restrict__ f2g_w, const float* __restrict__ f2g_b,
    const float* __restrict__ f2b_w, const float* __restrict__ f2b_b,
    float* __restrict__ G2, float* __restrict__ B2)
{
    const int o = blockIdx.x;
    const int lane = threadIdx.x & 63, w = threadIdx.x >> 6;
    const float4 wg = *(const float4*)(f2g_w + o*256 + lane*4);
    const float4 wb = *(const float4*)(f2b_w + o*256 + lane*4);
    #pragma unroll
    for (int bb = 0; bb < 4; ++bb) {
        const int b = w*4 + bb;
        const float4 u = *(const float4*)(CUE2 + b*256 + lane*4);
        float g = 0.f, bt = 0.f;
        #pragma unroll
        for (int i = 0; i < 4; ++i) {
            g  = fmaf(f4c(u,i), f4c(wg,i), g);
            bt = fmaf(f4c(u,i), f4c(wb,i), bt);
        }
        g = waveRed64(g); bt = waveRed64(bt);
        if (lane == 0) {
            G2[b*128 + o] = fmaxf(g + f2g_b[o], 0.f) + 1.f;
            B2[b*128 + o] = fmaxf(bt + f2b_b[o], 0.f);
        }
    }
}

// ---------------------------------------------------------------------------
__device__ __forceinline__ float blockSum256(float v, float* red)
{
    #pragma unroll
    for (int off = 32; off; off >>= 1) v += __shfl_down(v, off, 64);
    __syncthreads();
    if ((threadIdx.x & 63) == 0) red[threadIdx.x >> 6] = v;
    __syncthreads();
    return red[0] + red[1] + red[2] + red[3];
}

// ---------------------------------------------------------------------------
// kB0: per-batch stats chain -> a4, d4.  16 blocks x 256 thr.
// ---------------------------------------------------------------------------
__global__ __launch_bounds__(256) void kB0(
    const float* __restrict__ sp, const float* __restrict__ qp,
    const float* __restrict__ gn_a_w, const float* __restrict__ gn_a_b,
    const float* __restrict__ gn_n_w, const float* __restrict__ gn_n_b,
    const float* __restrict__ G1, const float* __restrict__ B1,
    const float* __restrict__ ln1_w, const float* __restrict__ ln1_b,
    float* __restrict__ a4o, float* __restrict__ d4o)
{
    const int b = blockIdx.x;
    const int c = threadIdx.x;
    __shared__ float red[4];

    float sc = 0.f, qc = 0.f;
    for (int i = 0; i < NTT; ++i) {
        sc += sp[((size_t)b*NTT + i)*256 + c];
        qc += qp[((size_t)b*NTT + i)*256 + c];
    }

    const float Ninv = 1.f / (256.f * 16000.f);
    const float Tf = 16000.f;

    float S  = blockSum256(sc, red);
    float Q  = blockSum256(qc, red);
    float mu1 = S * Ninv;
    float var1 = Q * Ninv - mu1 * mu1;
    float r1 = rsqrtf(var1 + EPSV);
    float a1 = gn_a_w[c] * r1;
    float d1 = gn_a_b[c] - mu1 * r1 * gn_a_w[c];

    float S2 = blockSum256(a1*sc + Tf*d1, red);
    float Q2 = blockSum256(a1*a1*qc + 2.f*a1*d1*sc + Tf*d1*d1, red);
    float mu2 = S2 * Ninv;
    float var2 = Q2 * Ninv - mu2 * mu2;
    float r2 = rsqrtf(var2 + EPSV);
    float wn = gn_n_w[c];
    float a2 = wn * r2 * a1;
    float d2 = wn * r2 * (d1 - mu2) + gn_n_b[c];

    const float g1 = G1[b*256 + c];
    const float b1 = B1[b*256 + c];
    float a3 = g1 * a2;
    float d3 = g1 * d2 + b1;

    float S3 = blockSum256(a3*sc + Tf*d3, red);
    float Q3 = blockSum256(a3*a3*qc + 2.f*a3*d3*sc + Tf*d3*d3, red);
    float mu3 = S3 * Ninv;
    float var3 = Q3 * Ninv - mu3 * mu3;
    float r3 = rsqrtf(var3 + EPSV);
    float w1 = ln1_w[c];
    a4o[b*256 + c] = w1 * r3 * a3;
    d4o[b*256 + c] = w1 * r3 * (d3 - mu3) + ln1_b[c];
}

// ---------------------------------------------------------------------------
// kE0: E[b][o] = G2*(conv1[o,:].d4[b,:]) + B2.  grid 128 (o) x 256 thr.
// ---------------------------------------------------------------------------
__global__ __launch_bounds__(256) void kE0(
    const float* __restrict__ d4, const float* __restrict__ G2,
    const float* __restrict__ B2, const float* __restrict__ conv1_w,
    float* __restrict__ E)
{
    const int o = blockIdx.x;
    const int lane = threadIdx.x & 63, w = threadIdx.x >> 6;
    const float4 wr = *(const float4*)(conv1_w + o*256 + lane*4);
    #pragma unroll
    for (int bb = 0; bb < 4; ++bb) {
        const int b = w*4 + bb;
        const float4 dv = *(const float4*)(d4 + b*256 + lane*4);
        float s = 0.f;
        #pragma unroll
        for (int i = 0; i < 4; ++i) s = fmaf(f4c(dv,i), f4c(wr,i), s);
        s = waveRed64(s);
        if (lane == 0) E[b*128 + o] = G2[b*128 + o] * s + B2[b*128 + o];
    }
}

// ---------------------------------------------------------------------------
// kM: Msf[b][o][c] = fp16(G2[b][o]*conv1[o][c]*a4[b][c]). grid (8,16) x 256.
// ---------------------------------------------------------------------------
__global__ __launch_bounds__(256) void kM(
    const float* __restrict__ a4, const float* __restrict__ G2,
    const float* __restrict__ conv1_w, ushort* __restrict__ Msf)
{
    const int og = blockIdx.x, b = blockIdx.y;
    const int c = threadIdx.x;
    const float a = a4[b*256 + c];
    #pragma unroll
    for (int i = 0; i < 16; ++i) {
        const int o = og*16 + i;
        Msf[((size_t)b*128 + o)*256 + c] = f2h(G2[b*128 + o] * conv1_w[o*256 + c] * a);
    }
}

// ---------------------------------------------------------------------------
// Kernel C: stats GEMM z2 = M x + e.  Block 128o x 128t, 4 waves (2o x 2t).
// ---------------------------------------------------------------------------
__global__ __launch_bounds__(256) void kC_gemm(
    const ushort* __restrict__ Xp, const ushort* __restrict__ Msf,
    const float* __restrict__ E,
    float* __restrict__ s2p, float* __restrict__ q2p)
{
    const int tb = blockIdx.x, b = blockIdx.y;
    const int tid = threadIdx.x, lane = tid & 63, w = tid >> 6;
    const int wo = w >> 1, wt = w & 1;
    const int sub = lane >> 4, li = lane & 15;
    const int o0 = wo * 64;
    __shared__ __align__(16) ushort Bs[2][8192];
    __shared__ float sSp[2][128], sQp[2][128];

    const ushort* src = Xp + ((size_t)(b*NTT + 2*tb)*4)*4096;
    const ushort* mp  = Msf + (size_t)b*128*256;

    f32x4 acc[4][4];
    #pragma unroll
    for (int i = 0; i < 4; ++i)
        #pragma unroll
        for (int jx = 0; jx < 4; ++jx) acc[i][jx] = (f32x4){0.f,0.f,0.f,0.f};

    #pragma unroll
    for (int jj = 0; jj < 4; ++jj) {
        const int m = w*4 + jj;
        const int ch = m >> 3, off = (m & 7)*512;
        gld16(src + (size_t)ch*16384 + off + lane*8, &Bs[0][ch*4096 + off]);
    }
    __syncthreads();
    for (int kc = 0; kc < 4; ++kc) {
        const int buf = kc & 1;
        if (kc < 3) {
            #pragma unroll
            for (int jj = 0; jj < 4; ++jj) {
                const int m = w*4 + jj;
                const int ch = m >> 3, off = (m & 7)*512;
                gld16(src + (size_t)ch*16384 + (kc+1)*4096 + off + lane*8,
                      &Bs[buf^1][ch*4096 + off]);
            }
        }
        f16x8 bfr[4][2];
        #pragma unroll
        for (int ft = 0; ft < 4; ++ft) {
            const int tl = ft*16 + li;
            #pragma unroll
            for (int ks = 0; ks < 2; ++ks) {
                const int u = (4*ks + sub) ^ (tl & 7);
                bfr[ft][ks] = *(const f16x8*)&Bs[buf][wt*4096 + tl*64 + u*8];
            }
        }
        #pragma unroll
        for (int ks = 0; ks < 2; ++ks) {
            #pragma unroll
            for (int fo = 0; fo < 4; ++fo) {
                const f16x8 a = *(const f16x8*)(mp + (size_t)(o0 + fo*16 + li)*256 + kc*64 + ks*32 + 8*sub);
                #pragma unroll
                for (int ft = 0; ft < 4; ++ft)
                    acc[fo][ft] = __builtin_amdgcn_mfma_f32_16x16x32_f16(a, bfr[ft][ks], acc[fo][ft], 0, 0, 0);
            }
        }
        __syncthreads();
    }

    #pragma unroll
    for (int fo = 0; fo < 4; ++fo) {
        #pragma unroll
        for (int r = 0; r < 4; ++r) {
            const int o = o0 + fo*16 + sub*4 + r;
            const float ev = E[b*128 + o];
            float sv = 0.f, qv = 0.f;
            #pragma unroll
            for (int ft = 0; ft < 4; ++ft) {
                const float z = acc[fo][ft][r] + ev;
                sv += z; qv += z*z;
            }
            #pragma unroll
            for (int m = 1; m <= 8; m <<= 1) {
                sv += __shfl_xor(sv, m, 64);
                qv += __shfl_xor(qv, m, 64);
            }
            if (li == 0) { sSp[wt][o] = sv; sQp[wt][o] = qv; }
        }
    }
    __syncthreads();
    if (tid < 128) {
        s2p[((size_t)b*NTB + tb)*128 + tid] = sSp[0][tid] + sSp[1][tid];
        q2p[((size_t)b*NTB + tb)*128 + tid] = sQp[0][tid] + sQp[1][tid];
    }
}

// ---------------------------------------------------------------------------
// Kernel E: out = F x + h.  Block 256o x 64t, 4 waves = 4 o-strips.
// ---------------------------------------------------------------------------
__global__ __launch_bounds__(256) void kE_gemm(
    const ushort* __restrict__ Xp, const ushort* __restrict__ Fsf,
    const float* __restrict__ h, float* __restrict__ out)
{
    const int tt = blockIdx.x, b = blockIdx.y;
    const int tid = threadIdx.x, lane = tid & 63, w = tid >> 6;
    const int sub = lane >> 4, li = lane & 15;
    const int o0 = w * 64, t0 = tt * 64;
    __shared__ __align__(16) ushort Bs[2][4096];

    const ushort* src = Xp + ((size_t)(b*NTT + tt)*4)*4096;
    const ushort* fp  = Fsf + (size_t)b*65536;

    f32x4 acc[4][4];
    #pragma unroll
    for (int i = 0; i < 4; ++i)
        #pragma unroll
        for (int jx = 0; jx < 4; ++jx) acc[i][jx] = (f32x4){0.f,0.f,0.f,0.f};

    #pragma unroll
    for (int jj = 0; jj < 2; ++jj) {
        const int m = w*2 + jj;
        gld16(src + m*512 + lane*8, &Bs[0][m*512]);
    }
    __syncthreads();
    for (int kc = 0; kc < 4; ++kc) {
        const int buf = kc & 1;
        if (kc < 3) {
            #pragma unroll
            for (int jj = 0; jj < 2; ++jj) {
                const int m = w*2 + jj;
                gld16(src + (kc+1)*4096 + m*512 + lane*8, &Bs[buf^1][m*512]);
            }
        }
        f16x8 bfr[4][2];
        #pragma unroll
        for (int ft = 0; ft < 4; ++ft) {
            const int t = ft*16 + li;
            #pragma unroll
            for (int ks = 0; ks < 2; ++ks) {
                const int u = (4*ks + sub) ^ (t & 7);
                bfr[ft][ks] = *(const f16x8*)&Bs[buf][t*64 + u*8];
            }
        }
        #pragma unroll
        for (int ks = 0; ks < 2; ++ks) {
            #pragma unroll
            for (int fo = 0; fo < 4; ++fo) {
                const f16x8 a = *(const f16x8*)(fp + (size_t)(o0 + fo*16 + li)*256 + kc*64 + ks*32 + 8*sub);
                #pragma unroll
                for (int ft = 0; ft < 4; ++ft)
                    acc[fo][ft] = __builtin_amdgcn_mfma_f32_16x16x32_f16(a, bfr[ft][ks], acc[fo][ft], 0, 0, 0);
            }
        }
        __syncthreads();
    }

    #pragma unroll
    for (int fo = 0; fo < 4; ++fo) {
        #pragma unroll
        for (int r = 0; r < 4; ++r) {
            const int o = o0 + fo*16 + sub*4 + r;
            const float hv = h[b*256 + o];
            float* op = out + ((size_t)(b*256 + o))*T_LEN + t0;
            #pragma unroll
            for (int ft = 0; ft < 4; ++ft)
                op[ft*16 + li] = acc[fo][ft][r] + hv;
        }
    }
}

// ---------------------------------------------------------------------------
// Kernel D1: finalize GN-4 stats -> A2, D2, AE (=A2*E+D2).
// ---------------------------------------------------------------------------
__global__ __launch_bounds__(128) void kD1_finalize(
    const float* __restrict__ s2p, const float* __restrict__ q2p,
    const float* __restrict__ ln2_w, const float* __restrict__ ln2_b,
    const float* __restrict__ E,
    float* __restrict__ A2, float* __restrict__ AE)
{
    const int b = blockIdx.x;
    const int o = threadIdx.x;
    float s = 0.f, qq = 0.f;
    for (int tb = 0; tb < NTB; ++tb) {
        s  += s2p[((size_t)b*NTB + tb)*128 + o];
        qq += q2p[((size_t)b*NTB + tb)*128 + o];
    }
    float S = s, Q = qq;
    #pragma unroll
    for (int off = 32; off; off >>= 1) {
        S += __shfl_down(S, off, 64);
        Q += __shfl_down(Q, off, 64);
    }
    __shared__ float rS[2], rQ[2];
    if ((o & 63) == 0) { rS[o >> 6] = S; rQ[o >> 6] = Q; }
    __syncthreads();
    const float N2inv = 1.f / (128.f * 16000.f);
    const float mu  = (rS[0] + rS[1]) * N2inv;
    const float var = (rQ[0] + rQ[1]) * N2inv - mu * mu;
    const float r = rsqrtf(var + EPSV);
    const float a2v = ln2_w[o] * r;
    const float d2v = ln2_b[o] - mu * ln2_w[o] * r;
    A2[b*128 + o] = a2v;
    AE[b*128 + o] = a2v * E[b*128 + o] + d2v;
}

// ---------------------------------------------------------------------------
// Kernel D2: F = [conv2*diag(A2*G2)*conv1]*diag(a4) (fp16); h = conv2.AE.
// grid (8 pg, 16 b) x 256 thr.
// ---------------------------------------------------------------------------
__global__ __launch_bounds__(256) void kD2_buildF(
    const float* __restrict__ a4, const float* __restrict__ G2,
    const float* __restrict__ A2, const float* __restrict__ AE,
    const float* __restrict__ conv1_w, const float* __restrict__ conv2_w,
    ushort* __restrict__ Fsf, float* __restrict__ h)
{
    const int b = blockIdx.y, pg = blockIdx.x;
    const int tid = threadIdx.x;
    __shared__ float Qs[32][128];
    #pragma unroll
    for (int k = 0; k < 16; ++k) {
        const int idx = tid + k*256;
        const int p = idx >> 7, o = idx & 127;
        Qs[p][o] = conv2_w[(pg*32 + p)*128 + o] * A2[b*128 + o] * G2[b*128 + o];
    }
    __syncthreads();
    float acc[32];
    #pragma unroll
    for (int p = 0; p < 32; ++p) acc[p] = 0.f;
    for (int o = 0; o < 128; ++o) {
        const float mv = conv1_w[o*256 + tid];
        #pragma unroll
        for (int p = 0; p < 32; ++p) acc[p] = fmaf(Qs[p][o], mv, acc[p]);
    }
    const float a = a4[b*256 + tid];
    #pragma unroll
    for (int p = 0; p < 32; ++p) {
        const size_t idx = ((size_t)b*256 + pg*32 + p)*256 + tid;
        Fsf[idx] = f2h(acc[p] * a);
    }
    if (tid < 32) {
        const int p = pg*32 + tid;
        float hv = 0.f;
        for (int o = 0; o < 128; ++o)
            hv += conv2_w[p*128 + o] * AE[b*128 + o];
        h[b*256 + p] = hv;
    }
}

// ---------------------------------------------------------------------------
extern "C" void kernel_launch(void* const* d_in, const int* in_sizes, int n_in,
                              void* d_out, int out_size, void* d_ws, size_t ws_size,
                              hipStream_t stream)
{
    const float* x       = (const float*)d_in[0];
    const float* cue     = (const float*)d_in[1];
    const float* gn_a_w  = (const float*)d_in[2];
    const float* gn_a_b  = (const float*)d_in[3];
    const float* gn_n_w  = (const float*)d_in[4];
    const float* gn_n_b  = (const float*)d_in[5];
    const float* f1g_w   = (const float*)d_in[6];
    const float* f1g_b   = (const float*)d_in[7];
    const float* f1b_w   = (const float*)d_in[8];
    const float* f1b_b   = (const float*)d_in[9];
    const float* ln1_w   = (const float*)d_in[10];
    const float* ln1_b   = (const float*)d_in[11];
    const float* conv1_w = (const float*)d_in[12];
    const float* cds_w   = (const float*)d_in[13];
    const float* f2g_w   = (const float*)d_in[14];
    const float* f2g_b   = (const float*)d_in[15];
    const float* f2b_w   = (const float*)d_in[16];
    const float* f2b_b   = (const float*)d_in[17];
    const float* ln2_w   = (const float*)d_in[18];
    const float* ln2_b   = (const float*)d_in[19];
    const float* conv2_w = (const float*)d_in[20];
    float* out = (float*)d_out;

    float* ws = (float*)d_ws;
    float*  sp   = ws;                       // 1,024,000
    float*  qp   = ws + 1024000;             // 1,024,000
    float*  G1   = ws + 2048000;             // 4,096
    float*  B1   = ws + 2052096;             // 4,096
    float*  CUE2 = ws + 2056192;             // 4,096
    float*  G2   = ws + 2060288;             // 2,048
    float*  B2   = ws + 2062336;             // 2,048
    float*  a4   = ws + 2064384;             // 4,096
    float*  d4   = ws + 2068480;             // 4,096
    float*  E    = ws + 2072576;             // 2,048
    float*  A2   = ws + 2074624;             // 2,048
    float*  AE   = ws + 2076672;             // 2,048
    float*  h    = ws + 2078720;             // 4,096
    float*  s2p  = ws + 2082816;             // 256,000
    float*  q2p  = ws + 2338816;             // 256,000
    ushort* Msf  = (ushort*)(ws + 2594816);  // 524,288 ush
    ushort* Fsf  = (ushort*)(ws + 2856960);  // 1,048,576 ush
    ushort* Xp   = (ushort*)(ws + 3381248);  // 65,536,000 ush
    // total ~ 36,149,248 floats ~= 144.6 MB

    kP1_split<<<dim3(NTT, NB), 256, 0, stream>>>(x, Xp, sp, qp);

    kW1<<<256, 256, 0, stream>>>(cue, f1g_w, f1g_b, f1b_w, f1b_b, cds_w,
                                 G1, B1, CUE2);

    kW2<<<128, 256, 0, stream>>>(CUE2, f2g_w, f2g_b, f2b_w, f2b_b, G2, B2);

    kB0<<<NB, 256, 0, stream>>>(sp, qp, gn_a_w, gn_a_b, gn_n_w, gn_n_b,
                                G1, B1, ln1_w, ln1_b, a4, d4);

    kE0<<<128, 256, 0, stream>>>(d4, G2, B2, conv1_w, E);

    kM<<<dim3(8, NB), 256, 0, stream>>>(a4, G2, conv1_w, Msf);

    kC_gemm<<<dim3(NTB, NB), 256, 0, stream>>>(Xp, Msf, E, s2p, q2p);

    kD1_finalize<<<NB, 128, 0, stream>>>(s2p, q2p, ln2_w, ln2_b, E, A2, AE);

    kD2_buildF<<<dim3(8, NB), 256, 0, stream>>>(a4, G2, A2, AE,
                                                conv1_w, conv2_w, Fsf, h);

    kE_gemm<<<dim3(NTT, NB), 256, 0, stream>>>(Xp, Fsf, h, out);
}

// Round 6
// 322.126 us; speedup vs baseline: 2.4249x; 1.1236x over previous
//
#include <hip/hip_runtime.h>
#include <hip/hip_bf16.h>
#include <hip/hip_fp16.h>

#define T_LEN   16000
#define NB      16
#define NTT     250         // T_LEN / 64 : plane chunks & kP1/kE tiles
#define NTB     125         // T_LEN / 128: kC tiles
#define EPSV    1e-8f

typedef _Float16 f16x8 __attribute__((ext_vector_type(8)));
typedef float    f32x4 __attribute__((ext_vector_type(4)));
typedef float    f32x4v __attribute__((ext_vector_type(4)));

__device__ __forceinline__ ushort f2h(float f) {
    _Float16 h = (_Float16)f;
    return *(ushort*)&h;
}
__device__ __forceinline__ float f4c(const float4& v, int i) {
    return i == 0 ? v.x : i == 1 ? v.y : i == 2 ? v.z : v.w;
}
__device__ __forceinline__ void gld16(const ushort* g, ushort* l) {
    __builtin_amdgcn_global_load_lds(
        (const __attribute__((address_space(1))) uint*)g,
        (__attribute__((address_space(3))) uint*)l, 16, 0, 0);
}
__device__ __forceinline__ float waveRed64(float v) {
    #pragma unroll
    for (int m = 1; m <= 32; m <<= 1) v += __shfl_xor(v, m, 64);
    return v;
}
__device__ __forceinline__ float4 ntload4(const float* p) {
    f32x4v v = __builtin_nontemporal_load((const f32x4v*)p);
    return make_float4(v[0], v[1], v[2], v[3]);
}

// ---------------------------------------------------------------------------
// Pass 1: read X once (nontemporal) -> per-(b,c) partial s,q + fp16 plane.
// Plane: Xp[b][tt][kc] = 8KB chunk of 64t x 64k fp16; 16B unit (t,u) at
// (t*8 + (u^(t&7)))*8 ushorts. grid (250,16) x 256.
// ---------------------------------------------------------------------------
__global__ __launch_bounds__(256) void kP1_split(
    const float* __restrict__ x, ushort* __restrict__ Xp,
    float* __restrict__ sp, float* __restrict__ qp)
{
    const int tt = blockIdx.x, b = blockIdx.y;
    const int t0 = tt * 64;
    const int tid = threadIdx.x;
    const int j = tid & 15, cg = tid >> 4;
    __shared__ __align__(16) ushort Hs[64][264];

    #pragma unroll
    for (int p = 0; p < 4; ++p) {
        #pragma unroll
        for (int k = 0; k < 4; ++k) {
            const int c = k*64 + p*16 + cg;
            const float4 v = ntload4(x + ((size_t)(b*256 + c))*T_LEN + t0 + j*4);
            float s4 = 0.f, q4 = 0.f;
            #pragma unroll
            for (int i = 0; i < 4; ++i) {
                const float f = f4c(v, i);
                s4 += f; q4 += f*f;
                Hs[j*4 + i][c] = f2h(f);
            }
            #pragma unroll
            for (int m = 1; m <= 8; m <<= 1) {
                s4 += __shfl_xor(s4, m, 16);
                q4 += __shfl_xor(q4, m, 16);
            }
            if (j == 0) {
                sp[((size_t)b*NTT + tt)*256 + c] = s4;
                qp[((size_t)b*NTT + tt)*256 + c] = q4;
            }
        }
    }
    __syncthreads();
    ushort* dst = Xp + ((size_t)(b*NTT + tt)*4)*4096;
    #pragma unroll
    for (int k = 0; k < 8; ++k) {
        const int d  = tid + k*256;
        const int kc = d >> 9, r = d & 511;
        const int t  = r >> 3, us = r & 7;
        const int u  = us ^ (t & 7);
        *(uint4*)(dst + (size_t)d*8) = *(const uint4*)&Hs[t][kc*64 + u*8];
    }
}

// ---------------------------------------------------------------------------
// kW1: per-channel cue GEMVs. G1=relu(f1g.cue+b)+1, B1=relu(f1b.cue+b),
// CUE2=relu(cds.cue).  grid 256 (c) x 256 thr; wave w -> batches 4w..4w+3.
// ---------------------------------------------------------------------------
__global__ __launch_bounds__(256) void kW1(
    const float* __restrict__ cue,
    const float* __restrict__ f1g_w, const float* __restrict__ f1g_b,
    const float* __restrict__ f1b_w, const float* __restrict__ f1b_b,
    const float* __restrict__ cds_w,
    float* __restrict__ G1, float* __restrict__ B1, float* __restrict__ CUE2)
{
    const int c = blockIdx.x;
    const int lane = threadIdx.x & 63, w = threadIdx.x >> 6;
    const float4 wg0 = *(const float4*)(f1g_w + c*512 + lane*8);
    const float4 wg1 = *(const float4*)(f1g_w + c*512 + lane*8 + 4);
    const float4 wb0 = *(const float4*)(f1b_w + c*512 + lane*8);
    const float4 wb1 = *(const float4*)(f1b_w + c*512 + lane*8 + 4);
    const float4 wc0 = *(const float4*)(cds_w + c*512 + lane*8);
    const float4 wc1 = *(const float4*)(cds_w + c*512 + lane*8 + 4);
    #pragma unroll
    for (int bb = 0; bb < 4; ++bb) {
        const int b = w*4 + bb;
        const float4 u0 = *(const float4*)(cue + b*512 + lane*8);
        const float4 u1 = *(const float4*)(cue + b*512 + lane*8 + 4);
        float g = 0.f, bt = 0.f, cv = 0.f;
        #pragma unroll
        for (int i = 0; i < 4; ++i) {
            g  = fmaf(f4c(u0,i), f4c(wg0,i), g);  g  = fmaf(f4c(u1,i), f4c(wg1,i), g);
            bt = fmaf(f4c(u0,i), f4c(wb0,i), bt); bt = fmaf(f4c(u1,i), f4c(wb1,i), bt);
            cv = fmaf(f4c(u0,i), f4c(wc0,i), cv); cv = fmaf(f4c(u1,i), f4c(wc1,i), cv);
        }
        g = waveRed64(g); bt = waveRed64(bt); cv = waveRed64(cv);
        if (lane == 0) {
            G1[b*256 + c]   = fmaxf(g + f1g_b[c], 0.f) + 1.f;
            B1[b*256 + c]   = fmaxf(bt + f1b_b[c], 0.f);
            CUE2[b*256 + c] = fmaxf(cv, 0.f);
        }
    }
}

// ---------------------------------------------------------------------------
__device__ __forceinline__ float blockSum256(float v, float* red)
{
    #pragma unroll
    for (int off = 32; off; off >>= 1) v += __shfl_down(v, off, 64);
    __syncthreads();
    if ((threadIdx.x & 63) == 0) red[threadIdx.x >> 6] = v;
    __syncthreads();
    return red[0] + red[1] + red[2] + red[3];
}

// ---------------------------------------------------------------------------
// kB0: per-batch stats chain -> a4, d4.  16 blocks x 256 thr.
// ---------------------------------------------------------------------------
__global__ __launch_bounds__(256) void kB0(
    const float* __restrict__ sp, const float* __restrict__ qp,
    const float* __restrict__ gn_a_w, const float* __restrict__ gn_a_b,
    const float* __restrict__ gn_n_w, const float* __restrict__ gn_n_b,
    const float* __restrict__ G1, const float* __restrict__ B1,
    const float* __restrict__ ln1_w, const float* __restrict__ ln1_b,
    float* __restrict__ a4o, float* __restrict__ d4o)
{
    const int b = blockIdx.x;
    const int c = threadIdx.x;
    __shared__ float red[4];

    float sc = 0.f, qc = 0.f;
    for (int i = 0; i < NTT; ++i) {
        sc += sp[((size_t)b*NTT + i)*256 + c];
        qc += qp[((size_t)b*NTT + i)*256 + c];
    }

    const float Ninv = 1.f / (256.f * 16000.f);
    const float Tf = 16000.f;

    float S  = blockSum256(sc, red);
    float Q  = blockSum256(qc, red);
    float mu1 = S * Ninv;
    float var1 = Q * Ninv - mu1 * mu1;
    float r1 = rsqrtf(var1 + EPSV);
    float a1 = gn_a_w[c] * r1;
    float d1 = gn_a_b[c] - mu1 * r1 * gn_a_w[c];

    float S2 = blockSum256(a1*sc + Tf*d1, red);
    float Q2 = blockSum256(a1*a1*qc + 2.f*a1*d1*sc + Tf*d1*d1, red);
    float mu2 = S2 * Ninv;
    float var2 = Q2 * Ninv - mu2 * mu2;
    float r2 = rsqrtf(var2 + EPSV);
    float wn = gn_n_w[c];
    float a2 = wn * r2 * a1;
    float d2 = wn * r2 * (d1 - mu2) + gn_n_b[c];

    const float g1 = G1[b*256 + c];
    const float b1 = B1[b*256 + c];
    float a3 = g1 * a2;
    float d3 = g1 * d2 + b1;

    float S3 = blockSum256(a3*sc + Tf*d3, red);
    float Q3 = blockSum256(a3*a3*qc + 2.f*a3*d3*sc + Tf*d3*d3, red);
    float mu3 = S3 * Ninv;
    float var3 = Q3 * Ninv - mu3 * mu3;
    float r3 = rsqrtf(var3 + EPSV);
    float w1 = ln1_w[c];
    a4o[b*256 + c] = w1 * r3 * a3;
    d4o[b*256 + c] = w1 * r3 * (d3 - mu3) + ln1_b[c];
}

// ---------------------------------------------------------------------------
// kM2 (fused kW2+kE0+kM): per (og,b): G2,B2 from CUE2; E = G2*(conv1.d4)+B2;
// Msf rows.  grid (8 og, 16 b) x 256 thr.
// ---------------------------------------------------------------------------
__global__ __launch_bounds__(256) void kM2(
    const float* __restrict__ CUE2,
    const float* __restrict__ f2g_w, const float* __restrict__ f2g_b,
    const float* __restrict__ f2b_w, const float* __restrict__ f2b_b,
    const float* __restrict__ conv1_w,
    const float* __restrict__ a4, const float* __restrict__ d4,
    float* __restrict__ G2, float* __restrict__ E, ushort* __restrict__ Msf)
{
    const int og = blockIdx.x, b = blockIdx.y;
    const int tid = threadIdx.x;
    __shared__ float sc2[256], sa4[256], sd4[256], sg2[16];
    sc2[tid] = CUE2[b*256 + tid];
    sa4[tid] = a4[b*256 + tid];
    sd4[tid] = d4[b*256 + tid];
    __syncthreads();

    const int oi = tid >> 4, l16 = tid & 15;
    const int o = og*16 + oi;
    float g = 0.f, bt = 0.f, ed = 0.f;
    #pragma unroll
    for (int q = 0; q < 4; ++q) {
        const int k0 = l16*16 + q*4;
        const float4 a  = *(const float4*)(f2g_w  + o*256 + k0);
        const float4 bb = *(const float4*)(f2b_w  + o*256 + k0);
        const float4 c  = *(const float4*)(conv1_w + o*256 + k0);
        const float4 u  = *(const float4*)(&sc2[k0]);
        const float4 dd = *(const float4*)(&sd4[k0]);
        #pragma unroll
        for (int i = 0; i < 4; ++i) {
            g  = fmaf(f4c(u,i),  f4c(a,i),  g);
            bt = fmaf(f4c(u,i),  f4c(bb,i), bt);
            ed = fmaf(f4c(dd,i), f4c(c,i),  ed);
        }
    }
    #pragma unroll
    for (int m = 1; m <= 8; m <<= 1) {
        g  += __shfl_xor(g, m, 16);
        bt += __shfl_xor(bt, m, 16);
        ed += __shfl_xor(ed, m, 16);
    }
    if (l16 == 0) {
        const float G2v = fmaxf(g + f2g_b[o], 0.f) + 1.f;
        const float B2v = fmaxf(bt + f2b_b[o], 0.f);
        G2[b*128 + o] = G2v;
        E[b*128 + o]  = G2v * ed + B2v;
        sg2[oi] = G2v;
    }
    __syncthreads();
    const float av = sa4[tid];
    #pragma unroll
    for (int i = 0; i < 16; ++i) {
        const int oo = og*16 + i;
        Msf[((size_t)b*128 + oo)*256 + tid] = f2h(sg2[i] * conv1_w[oo*256 + tid] * av);
    }
}

// ---------------------------------------------------------------------------
// Kernel C: stats GEMM z2 = M x + e.  Block 128o x 128t, 4 waves (2o x 2t).
// ---------------------------------------------------------------------------
__global__ __launch_bounds__(256) void kC_gemm(
    const ushort* __restrict__ Xp, const ushort* __restrict__ Msf,
    const float* __restrict__ E,
    float* __restrict__ s2p, float* __restrict__ q2p)
{
    const int tb = blockIdx.x, b = blockIdx.y;
    const int tid = threadIdx.x, lane = tid & 63, w = tid >> 6;
    const int wo = w >> 1, wt = w & 1;
    const int sub = lane >> 4, li = lane & 15;
    const int o0 = wo * 64;
    __shared__ __align__(16) ushort Bs[2][8192];
    __shared__ float sSp[2][128], sQp[2][128];

    const ushort* src = Xp + ((size_t)(b*NTT + 2*tb)*4)*4096;
    const ushort* mp  = Msf + (size_t)b*128*256;

    f32x4 acc[4][4];
    #pragma unroll
    for (int i = 0; i < 4; ++i)
        #pragma unroll
        for (int jx = 0; jx < 4; ++jx) acc[i][jx] = (f32x4){0.f,0.f,0.f,0.f};

    #pragma unroll
    for (int jj = 0; jj < 4; ++jj) {
        const int m = w*4 + jj;
        const int ch = m >> 3, off = (m & 7)*512;
        gld16(src + (size_t)ch*16384 + off + lane*8, &Bs[0][ch*4096 + off]);
    }
    __syncthreads();
    for (int kc = 0; kc < 4; ++kc) {
        const int buf = kc & 1;
        if (kc < 3) {
            #pragma unroll
            for (int jj = 0; jj < 4; ++jj) {
                const int m = w*4 + jj;
                const int ch = m >> 3, off = (m & 7)*512;
                gld16(src + (size_t)ch*16384 + (kc+1)*4096 + off + lane*8,
                      &Bs[buf^1][ch*4096 + off]);
            }
        }
        f16x8 bfr[4][2];
        #pragma unroll
        for (int ft = 0; ft < 4; ++ft) {
            const int tl = ft*16 + li;
            #pragma unroll
            for (int ks = 0; ks < 2; ++ks) {
                const int u = (4*ks + sub) ^ (tl & 7);
                bfr[ft][ks] = *(const f16x8*)&Bs[buf][wt*4096 + tl*64 + u*8];
            }
        }
        #pragma unroll
        for (int ks = 0; ks < 2; ++ks) {
            #pragma unroll
            for (int fo = 0; fo < 4; ++fo) {
                const f16x8 a = *(const f16x8*)(mp + (size_t)(o0 + fo*16 + li)*256 + kc*64 + ks*32 + 8*sub);
                #pragma unroll
                for (int ft = 0; ft < 4; ++ft)
                    acc[fo][ft] = __builtin_amdgcn_mfma_f32_16x16x32_f16(a, bfr[ft][ks], acc[fo][ft], 0, 0, 0);
            }
        }
        __syncthreads();
    }

    #pragma unroll
    for (int fo = 0; fo < 4; ++fo) {
        #pragma unroll
        for (int r = 0; r < 4; ++r) {
            const int o = o0 + fo*16 + sub*4 + r;
            const float ev = E[b*128 + o];
            float sv = 0.f, qv = 0.f;
            #pragma unroll
            for (int ft = 0; ft < 4; ++ft) {
                const float z = acc[fo][ft][r] + ev;
                sv += z; qv += z*z;
            }
            #pragma unroll
            for (int m = 1; m <= 8; m <<= 1) {
                sv += __shfl_xor(sv, m, 64);
                qv += __shfl_xor(qv, m, 64);
            }
            if (li == 0) { sSp[wt][o] = sv; sQp[wt][o] = qv; }
        }
    }
    __syncthreads();
    if (tid < 128) {
        s2p[((size_t)b*NTB + tb)*128 + tid] = sSp[0][tid] + sSp[1][tid];
        q2p[((size_t)b*NTB + tb)*128 + tid] = sQp[0][tid] + sQp[1][tid];
    }
}

// ---------------------------------------------------------------------------
// Kernel E: out = F x + h.  Block 256o x 64t, 4 waves = 4 o-strips.
// Epilogue: per-wave LDS transpose -> nontemporal dwordx4 stores (256B runs).
// ---------------------------------------------------------------------------
__global__ __launch_bounds__(256) void kE_gemm(
    const ushort* __restrict__ Xp, const ushort* __restrict__ Fsf,
    const float* __restrict__ h, float* __restrict__ out)
{
    const int tt = blockIdx.x, b = blockIdx.y;
    const int tid = threadIdx.x, lane = tid & 63, w = tid >> 6;
    const int sub = lane >> 4, li = lane & 15;
    const int o0 = w * 64, t0 = tt * 64;
    __shared__ __align__(16) ushort Bs[2][4096];
    __shared__ __align__(16) float Ts[4][16][68];   // per-wave transpose tile

    const ushort* src = Xp + ((size_t)(b*NTT + tt)*4)*4096;
    const ushort* fp  = Fsf + (size_t)b*65536;

    f32x4 acc[4][4];
    #pragma unroll
    for (int i = 0; i < 4; ++i)
        #pragma unroll
        for (int jx = 0; jx < 4; ++jx) acc[i][jx] = (f32x4){0.f,0.f,0.f,0.f};

    #pragma unroll
    for (int jj = 0; jj < 2; ++jj) {
        const int m = w*2 + jj;
        gld16(src + m*512 + lane*8, &Bs[0][m*512]);
    }
    __syncthreads();
    for (int kc = 0; kc < 4; ++kc) {
        const int buf = kc & 1;
        if (kc < 3) {
            #pragma unroll
            for (int jj = 0; jj < 2; ++jj) {
                const int m = w*2 + jj;
                gld16(src + (kc+1)*4096 + m*512 + lane*8, &Bs[buf^1][m*512]);
            }
        }
        f16x8 bfr[4][2];
        #pragma unroll
        for (int ft = 0; ft < 4; ++ft) {
            const int t = ft*16 + li;
            #pragma unroll
            for (int ks = 0; ks < 2; ++ks) {
                const int u = (4*ks + sub) ^ (t & 7);
                bfr[ft][ks] = *(const f16x8*)&Bs[buf][t*64 + u*8];
            }
        }
        #pragma unroll
        for (int ks = 0; ks < 2; ++ks) {
            #pragma unroll
            for (int fo = 0; fo < 4; ++fo) {
                const f16x8 a = *(const f16x8*)(fp + (size_t)(o0 + fo*16 + li)*256 + kc*64 + ks*32 + 8*sub);
                #pragma unroll
                for (int ft = 0; ft < 4; ++ft)
                    acc[fo][ft] = __builtin_amdgcn_mfma_f32_16x16x32_f16(a, bfr[ft][ks], acc[fo][ft], 0, 0, 0);
            }
        }
        __syncthreads();
    }

    // epilogue: wave-private LDS transpose, then 256B-contiguous nt stores
    #pragma unroll
    for (int fo = 0; fo < 4; ++fo) {
        float hv[4];
        #pragma unroll
        for (int r = 0; r < 4; ++r)
            hv[r] = h[b*256 + o0 + fo*16 + sub*4 + r];
        #pragma unroll
        for (int ft = 0; ft < 4; ++ft)
            #pragma unroll
            for (int r = 0; r < 4; ++r)
                Ts[w][sub*4 + r][ft*16 + li] = acc[fo][ft][r] + hv[r];
        #pragma unroll
        for (int it = 0; it < 4; ++it) {
            const int row = it*4 + sub;
            const f32x4v v = *(const f32x4v*)&Ts[w][row][li*4];
            __builtin_nontemporal_store(v,
                (f32x4v*)(out + ((size_t)(b*256 + o0 + fo*16 + row))*T_LEN + t0 + li*4));
        }
    }
}

// ---------------------------------------------------------------------------
// Kernel D1: finalize GN-4 stats -> A2, AE (=A2*E+D2).
// ---------------------------------------------------------------------------
__global__ __launch_bounds__(128) void kD1_finalize(
    const float* __restrict__ s2p, const float* __restrict__ q2p,
    const float* __restrict__ ln2_w, const float* __restrict__ ln2_b,
    const float* __restrict__ E,
    float* __restrict__ A2, float* __restrict__ AE)
{
    const int b = blockIdx.x;
    const int o = threadIdx.x;
    float s = 0.f, qq = 0.f;
    for (int tb = 0; tb < NTB; ++tb) {
        s  += s2p[((size_t)b*NTB + tb)*128 + o];
        qq += q2p[((size_t)b*NTB + tb)*128 + o];
    }
    float S = s, Q = qq;
    #pragma unroll
    for (int off = 32; off; off >>= 1) {
        S += __shfl_down(S, off, 64);
        Q += __shfl_down(Q, off, 64);
    }
    __shared__ float rS[2], rQ[2];
    if ((o & 63) == 0) { rS[o >> 6] = S; rQ[o >> 6] = Q; }
    __syncthreads();
    const float N2inv = 1.f / (128.f * 16000.f);
    const float mu  = (rS[0] + rS[1]) * N2inv;
    const float var = (rQ[0] + rQ[1]) * N2inv - mu * mu;
    const float r = rsqrtf(var + EPSV);
    const float a2v = ln2_w[o] * r;
    const float d2v = ln2_b[o] - mu * ln2_w[o] * r;
    A2[b*128 + o] = a2v;
    AE[b*128 + o] = a2v * E[b*128 + o] + d2v;
}

// ---------------------------------------------------------------------------
// Kernel D2: F = [conv2*diag(A2*G2)*conv1]*diag(a4) (fp16); h = conv2.AE.
// grid (8 pg, 16 b) x 256 thr.
// ---------------------------------------------------------------------------
__global__ __launch_bounds__(256) void kD2_buildF(
    const float* __restrict__ a4, const float* __restrict__ G2,
    const float* __restrict__ A2, const float* __restrict__ AE,
    const float* __restrict__ conv1_w, const float* __restrict__ conv2_w,
    ushort* __restrict__ Fsf, float* __restrict__ h)
{
    const int b = blockIdx.y, pg = blockIdx.x;
    const int tid = threadIdx.x;
    __shared__ float Qs[32][128];
    #pragma unroll
    for (int k = 0; k < 16; ++k) {
        const int idx = tid + k*256;
        const int p = idx >> 7, o = idx & 127;
        Qs[p][o] = conv2_w[(pg*32 + p)*128 + o] * A2[b*128 + o] * G2[b*128 + o];
    }
    __syncthreads();
    float acc[32];
    #pragma unroll
    for (int p = 0; p < 32; ++p) acc[p] = 0.f;
    for (int o = 0; o < 128; ++o) {
        const float mv = conv1_w[o*256 + tid];
        #pragma unroll
        for (int p = 0; p < 32; ++p) acc[p] = fmaf(Qs[p][o], mv, acc[p]);
    }
    const float a = a4[b*256 + tid];
    #pragma unroll
    for (int p = 0; p < 32; ++p) {
        const size_t idx = ((size_t)b*256 + pg*32 + p)*256 + tid;
        Fsf[idx] = f2h(acc[p] * a);
    }
    if (tid < 32) {
        const int p = pg*32 + tid;
        float hv = 0.f;
        for (int o = 0; o < 128; ++o)
            hv += conv2_w[p*128 + o] * AE[b*128 + o];
        h[b*256 + p] = hv;
    }
}

// ---------------------------------------------------------------------------
extern "C" void kernel_launch(void* const* d_in, const int* in_sizes, int n_in,
                              void* d_out, int out_size, void* d_ws, size_t ws_size,
                              hipStream_t stream)
{
    const float* x       = (const float*)d_in[0];
    const float* cue     = (const float*)d_in[1];
    const float* gn_a_w  = (const float*)d_in[2];
    const float* gn_a_b  = (const float*)d_in[3];
    const float* gn_n_w  = (const float*)d_in[4];
    const float* gn_n_b  = (const float*)d_in[5];
    const float* f1g_w   = (const float*)d_in[6];
    const float* f1g_b   = (const float*)d_in[7];
    const float* f1b_w   = (const float*)d_in[8];
    const float* f1b_b   = (const float*)d_in[9];
    const float* ln1_w   = (const float*)d_in[10];
    const float* ln1_b   = (const float*)d_in[11];
    const float* conv1_w = (const float*)d_in[12];
    const float* cds_w   = (const float*)d_in[13];
    const float* f2g_w   = (const float*)d_in[14];
    const float* f2g_b   = (const float*)d_in[15];
    const float* f2b_w   = (const float*)d_in[16];
    const float* f2b_b   = (const float*)d_in[17];
    const float* ln2_w   = (const float*)d_in[18];
    const float* ln2_b   = (const float*)d_in[19];
    const float* conv2_w = (const float*)d_in[20];
    float* out = (float*)d_out;

    float* ws = (float*)d_ws;
    float*  sp   = ws;                       // 1,024,000
    float*  qp   = ws + 1024000;             // 1,024,000
    float*  G1   = ws + 2048000;             // 4,096
    float*  B1   = ws + 2052096;             // 4,096
    float*  CUE2 = ws + 2056192;             // 4,096
    float*  G2   = ws + 2060288;             // 2,048
    float*  a4   = ws + 2062336;             // 4,096
    float*  d4   = ws + 2066432;             // 4,096
    float*  E    = ws + 2070528;             // 2,048
    float*  A2   = ws + 2072576;             // 2,048
    float*  AE   = ws + 2074624;             // 2,048
    float*  h    = ws + 2076672;             // 4,096
    float*  s2p  = ws + 2080768;             // 256,000
    float*  q2p  = ws + 2336768;             // 256,000
    ushort* Msf  = (ushort*)(ws + 2592768);  // 524,288 ush
    ushort* Fsf  = (ushort*)(ws + 2854912);  // 1,048,576 ush
    ushort* Xp   = (ushort*)(ws + 3379200);  // 65,536,000 ush
    // total ~ 36,147,200 floats ~= 144.6 MB

    kP1_split<<<dim3(NTT, NB), 256, 0, stream>>>(x, Xp, sp, qp);

    kW1<<<256, 256, 0, stream>>>(cue, f1g_w, f1g_b, f1b_w, f1b_b, cds_w,
                                 G1, B1, CUE2);

    kB0<<<NB, 256, 0, stream>>>(sp, qp, gn_a_w, gn_a_b, gn_n_w, gn_n_b,
                                G1, B1, ln1_w, ln1_b, a4, d4);

    kM2<<<dim3(8, NB), 256, 0, stream>>>(CUE2, f2g_w, f2g_b, f2b_w, f2b_b,
                                         conv1_w, a4, d4, G2, E, Msf);

    kC_gemm<<<dim3(NTB, NB), 256, 0, stream>>>(Xp, Msf, E, s2p, q2p);

    kD1_finalize<<<NB, 128, 0, stream>>>(s2p, q2p, ln2_w, ln2_b, E, A2, AE);

    kD2_buildF<<<dim3(8, NB), 256, 0, stream>>>(a4, G2, A2, AE,
                                                conv1_w, conv2_w, Fsf, h);

    kE_gemm<<<dim3(NTT, NB), 256, 0, stream>>>(Xp, Fsf, h, out);
}

// Round 7
// 313.705 us; speedup vs baseline: 2.4900x; 1.0268x over previous
//
#include <hip/hip_runtime.h>
#include <hip/hip_bf16.h>
#include <hip/hip_fp16.h>

#define T_LEN   16000
#define NB      16
#define NTT     250         // T_LEN / 64 : plane chunk granularity & kP1 tiles
#define NTB     125         // T_LEN / 128: kC / kE tiles
#define EPSV    1e-8f

typedef _Float16 f16x8 __attribute__((ext_vector_type(8)));
typedef float    f32x4 __attribute__((ext_vector_type(4)));

__device__ __forceinline__ ushort f2h(float f) {
    _Float16 h = (_Float16)f;
    return *(ushort*)&h;
}
__device__ __forceinline__ float f4c(const float4& v, int i) {
    return i == 0 ? v.x : i == 1 ? v.y : i == 2 ? v.z : v.w;
}
__device__ __forceinline__ void gld16(const ushort* g, ushort* l) {
    __builtin_amdgcn_global_load_lds(
        (const __attribute__((address_space(1))) uint*)g,
        (__attribute__((address_space(3))) uint*)l, 16, 0, 0);
}
__device__ __forceinline__ float waveRed64(float v) {
    #pragma unroll
    for (int m = 1; m <= 32; m <<= 1) v += __shfl_xor(v, m, 64);
    return v;
}
__device__ __forceinline__ float4 ntload4(const float* p) {
    f32x4 v = __builtin_nontemporal_load((const f32x4*)p);
    return make_float4(v[0], v[1], v[2], v[3]);
}

// ---------------------------------------------------------------------------
// Pass 1: read X once (nontemporal) -> per-(b,c) partial s,q + fp16 plane.
// Plane: Xp[b][tt][kc] = 8KB chunk of 64t x 64k fp16; 16B unit (t,u) at
// (t*8 + (u^(t&7)))*8 ushorts. grid (250,16) x 256.
// ---------------------------------------------------------------------------
__global__ __launch_bounds__(256) void kP1_split(
    const float* __restrict__ x, ushort* __restrict__ Xp,
    float* __restrict__ sp, float* __restrict__ qp)
{
    const int tt = blockIdx.x, b = blockIdx.y;
    const int t0 = tt * 64;
    const int tid = threadIdx.x;
    const int j = tid & 15, cg = tid >> 4;
    __shared__ __align__(16) ushort Hs[64][264];

    #pragma unroll
    for (int p = 0; p < 4; ++p) {
        #pragma unroll
        for (int k = 0; k < 4; ++k) {
            const int c = k*64 + p*16 + cg;
            const float4 v = ntload4(x + ((size_t)(b*256 + c))*T_LEN + t0 + j*4);
            float s4 = 0.f, q4 = 0.f;
            #pragma unroll
            for (int i = 0; i < 4; ++i) {
                const float f = f4c(v, i);
                s4 += f; q4 += f*f;
                Hs[j*4 + i][c] = f2h(f);
            }
            #pragma unroll
            for (int m = 1; m <= 8; m <<= 1) {
                s4 += __shfl_xor(s4, m, 16);
                q4 += __shfl_xor(q4, m, 16);
            }
            if (j == 0) {
                sp[((size_t)b*NTT + tt)*256 + c] = s4;
                qp[((size_t)b*NTT + tt)*256 + c] = q4;
            }
        }
    }
    __syncthreads();
    ushort* dst = Xp + ((size_t)(b*NTT + tt)*4)*4096;
    #pragma unroll
    for (int k = 0; k < 8; ++k) {
        const int d  = tid + k*256;
        const int kc = d >> 9, r = d & 511;
        const int t  = r >> 3, us = r & 7;
        const int u  = us ^ (t & 7);
        *(uint4*)(dst + (size_t)d*8) = *(const uint4*)&Hs[t][kc*64 + u*8];
    }
}

// ---------------------------------------------------------------------------
// kW1: per-channel cue GEMVs. G1=relu(f1g.cue+b)+1, B1=relu(f1b.cue+b),
// CUE2=relu(cds.cue).  grid 256 (c) x 256 thr; wave w -> batches 4w..4w+3.
// ---------------------------------------------------------------------------
__global__ __launch_bounds__(256) void kW1(
    const float* __restrict__ cue,
    const float* __restrict__ f1g_w, const float* __restrict__ f1g_b,
    const float* __restrict__ f1b_w, const float* __restrict__ f1b_b,
    const float* __restrict__ cds_w,
    float* __restrict__ G1, float* __restrict__ B1, float* __restrict__ CUE2)
{
    const int c = blockIdx.x;
    const int lane = threadIdx.x & 63, w = threadIdx.x >> 6;
    const float4 wg0 = *(const float4*)(f1g_w + c*512 + lane*8);
    const float4 wg1 = *(const float4*)(f1g_w + c*512 + lane*8 + 4);
    const float4 wb0 = *(const float4*)(f1b_w + c*512 + lane*8);
    const float4 wb1 = *(const float4*)(f1b_w + c*512 + lane*8 + 4);
    const float4 wc0 = *(const float4*)(cds_w + c*512 + lane*8);
    const float4 wc1 = *(const float4*)(cds_w + c*512 + lane*8 + 4);
    #pragma unroll
    for (int bb = 0; bb < 4; ++bb) {
        const int b = w*4 + bb;
        const float4 u0 = *(const float4*)(cue + b*512 + lane*8);
        const float4 u1 = *(const float4*)(cue + b*512 + lane*8 + 4);
        float g = 0.f, bt = 0.f, cv = 0.f;
        #pragma unroll
        for (int i = 0; i < 4; ++i) {
            g  = fmaf(f4c(u0,i), f4c(wg0,i), g);  g  = fmaf(f4c(u1,i), f4c(wg1,i), g);
            bt = fmaf(f4c(u0,i), f4c(wb0,i), bt); bt = fmaf(f4c(u1,i), f4c(wb1,i), bt);
            cv = fmaf(f4c(u0,i), f4c(wc0,i), cv); cv = fmaf(f4c(u1,i), f4c(wc1,i), cv);
        }
        g = waveRed64(g); bt = waveRed64(bt); cv = waveRed64(cv);
        if (lane == 0) {
            G1[b*256 + c]   = fmaxf(g + f1g_b[c], 0.f) + 1.f;
            B1[b*256 + c]   = fmaxf(bt + f1b_b[c], 0.f);
            CUE2[b*256 + c] = fmaxf(cv, 0.f);
        }
    }
}

// ---------------------------------------------------------------------------
__device__ __forceinline__ float blockSum256(float v, float* red)
{
    #pragma unroll
    for (int off = 32; off; off >>= 1) v += __shfl_down(v, off, 64);
    __syncthreads();
    if ((threadIdx.x & 63) == 0) red[threadIdx.x >> 6] = v;
    __syncthreads();
    return red[0] + red[1] + red[2] + red[3];
}

// ---------------------------------------------------------------------------
// kBM (fused kB0 + kM2): per-batch stats chain -> a4,d4 (LDS), then
// G2/E/Msf production looping og=0..7.  grid 16 (b) x 256 thr.
// ---------------------------------------------------------------------------
__global__ __launch_bounds__(256) void kBM(
    const float* __restrict__ sp, const float* __restrict__ qp,
    const float* __restrict__ gn_a_w, const float* __restrict__ gn_a_b,
    const float* __restrict__ gn_n_w, const float* __restrict__ gn_n_b,
    const float* __restrict__ G1, const float* __restrict__ B1,
    const float* __restrict__ ln1_w, const float* __restrict__ ln1_b,
    const float* __restrict__ CUE2,
    const float* __restrict__ f2g_w, const float* __restrict__ f2g_b,
    const float* __restrict__ f2b_w, const float* __restrict__ f2b_b,
    const float* __restrict__ conv1_w,
    float* __restrict__ a4o, float* __restrict__ G2,
    float* __restrict__ E, ushort* __restrict__ Msf)
{
    const int b = blockIdx.x;
    const int c = threadIdx.x;
    __shared__ float red[4];
    __shared__ float sa4[256], sd4[256], sc2[256], sg2[16];

    // ---- phase 1: stats chain (kB0) ----
    float sc = 0.f, qc = 0.f;
    for (int i = 0; i < NTT; ++i) {
        sc += sp[((size_t)b*NTT + i)*256 + c];
        qc += qp[((size_t)b*NTT + i)*256 + c];
    }

    const float Ninv = 1.f / (256.f * 16000.f);
    const float Tf = 16000.f;

    float S  = blockSum256(sc, red);
    float Q  = blockSum256(qc, red);
    float mu1 = S * Ninv;
    float var1 = Q * Ninv - mu1 * mu1;
    float r1 = rsqrtf(var1 + EPSV);
    float a1 = gn_a_w[c] * r1;
    float d1 = gn_a_b[c] - mu1 * r1 * gn_a_w[c];

    float S2 = blockSum256(a1*sc + Tf*d1, red);
    float Q2 = blockSum256(a1*a1*qc + 2.f*a1*d1*sc + Tf*d1*d1, red);
    float mu2 = S2 * Ninv;
    float var2 = Q2 * Ninv - mu2 * mu2;
    float r2 = rsqrtf(var2 + EPSV);
    float wn = gn_n_w[c];
    float a2 = wn * r2 * a1;
    float d2 = wn * r2 * (d1 - mu2) + gn_n_b[c];

    const float g1 = G1[b*256 + c];
    const float b1 = B1[b*256 + c];
    float a3 = g1 * a2;
    float d3 = g1 * d2 + b1;

    float S3 = blockSum256(a3*sc + Tf*d3, red);
    float Q3 = blockSum256(a3*a3*qc + 2.f*a3*d3*sc + Tf*d3*d3, red);
    float mu3 = S3 * Ninv;
    float var3 = Q3 * Ninv - mu3 * mu3;
    float r3 = rsqrtf(var3 + EPSV);
    float w1 = ln1_w[c];
    const float a4v = w1 * r3 * a3;
    const float d4v = w1 * r3 * (d3 - mu3) + ln1_b[c];
    sa4[c] = a4v;
    sd4[c] = d4v;
    a4o[b*256 + c] = a4v;
    sc2[c] = CUE2[b*256 + c];
    __syncthreads();

    // ---- phase 2: per-og G2/E/Msf (kM2) ----
    const int oi = c >> 4, l16 = c & 15;
    for (int og = 0; og < 8; ++og) {
        const int o = og*16 + oi;
        float g = 0.f, bt = 0.f, ed = 0.f;
        #pragma unroll
        for (int q = 0; q < 4; ++q) {
            const int k0 = l16*16 + q*4;
            const float4 a  = *(const float4*)(f2g_w  + o*256 + k0);
            const float4 bb = *(const float4*)(f2b_w  + o*256 + k0);
            const float4 cc = *(const float4*)(conv1_w + o*256 + k0);
            const float4 u  = *(const float4*)(&sc2[k0]);
            const float4 dd = *(const float4*)(&sd4[k0]);
            #pragma unroll
            for (int i = 0; i < 4; ++i) {
                g  = fmaf(f4c(u,i),  f4c(a,i),  g);
                bt = fmaf(f4c(u,i),  f4c(bb,i), bt);
                ed = fmaf(f4c(dd,i), f4c(cc,i), ed);
            }
        }
        #pragma unroll
        for (int m = 1; m <= 8; m <<= 1) {
            g  += __shfl_xor(g, m, 16);
            bt += __shfl_xor(bt, m, 16);
            ed += __shfl_xor(ed, m, 16);
        }
        if (l16 == 0) {
            const float G2v = fmaxf(g + f2g_b[o], 0.f) + 1.f;
            const float B2v = fmaxf(bt + f2b_b[o], 0.f);
            G2[b*128 + o] = G2v;
            E[b*128 + o]  = G2v * ed + B2v;
            sg2[oi] = G2v;
        }
        __syncthreads();
        const float av = sa4[c];
        #pragma unroll
        for (int i = 0; i < 16; ++i) {
            const int oo = og*16 + i;
            Msf[((size_t)b*128 + oo)*256 + c] = f2h(sg2[i] * conv1_w[oo*256 + c] * av);
        }
        __syncthreads();
    }
}

// ---------------------------------------------------------------------------
// Kernel C: stats GEMM z2 = M x + e.  Block 128o x 128t, 4 waves (2o x 2t).
// ---------------------------------------------------------------------------
__global__ __launch_bounds__(256) void kC_gemm(
    const ushort* __restrict__ Xp, const ushort* __restrict__ Msf,
    const float* __restrict__ E,
    float* __restrict__ s2p, float* __restrict__ q2p)
{
    const int tb = blockIdx.x, b = blockIdx.y;
    const int tid = threadIdx.x, lane = tid & 63, w = tid >> 6;
    const int wo = w >> 1, wt = w & 1;
    const int sub = lane >> 4, li = lane & 15;
    const int o0 = wo * 64;
    __shared__ __align__(16) ushort Bs[2][8192];
    __shared__ float sSp[2][128], sQp[2][128];

    const ushort* src = Xp + ((size_t)(b*NTT + 2*tb)*4)*4096;
    const ushort* mp  = Msf + (size_t)b*128*256;

    f32x4 acc[4][4];
    #pragma unroll
    for (int i = 0; i < 4; ++i)
        #pragma unroll
        for (int jx = 0; jx < 4; ++jx) acc[i][jx] = (f32x4){0.f,0.f,0.f,0.f};

    #pragma unroll
    for (int jj = 0; jj < 4; ++jj) {
        const int m = w*4 + jj;
        const int ch = m >> 3, off = (m & 7)*512;
        gld16(src + (size_t)ch*16384 + off + lane*8, &Bs[0][ch*4096 + off]);
    }
    __syncthreads();
    for (int kc = 0; kc < 4; ++kc) {
        const int buf = kc & 1;
        if (kc < 3) {
            #pragma unroll
            for (int jj = 0; jj < 4; ++jj) {
                const int m = w*4 + jj;
                const int ch = m >> 3, off = (m & 7)*512;
                gld16(src + (size_t)ch*16384 + (kc+1)*4096 + off + lane*8,
                      &Bs[buf^1][ch*4096 + off]);
            }
        }
        f16x8 bfr[4][2];
        #pragma unroll
        for (int ft = 0; ft < 4; ++ft) {
            const int tl = ft*16 + li;
            #pragma unroll
            for (int ks = 0; ks < 2; ++ks) {
                const int u = (4*ks + sub) ^ (tl & 7);
                bfr[ft][ks] = *(const f16x8*)&Bs[buf][wt*4096 + tl*64 + u*8];
            }
        }
        #pragma unroll
        for (int ks = 0; ks < 2; ++ks) {
            #pragma unroll
            for (int fo = 0; fo < 4; ++fo) {
                const f16x8 a = *(const f16x8*)(mp + (size_t)(o0 + fo*16 + li)*256 + kc*64 + ks*32 + 8*sub);
                #pragma unroll
                for (int ft = 0; ft < 4; ++ft)
                    acc[fo][ft] = __builtin_amdgcn_mfma_f32_16x16x32_f16(a, bfr[ft][ks], acc[fo][ft], 0, 0, 0);
            }
        }
        __syncthreads();
    }

    #pragma unroll
    for (int fo = 0; fo < 4; ++fo) {
        #pragma unroll
        for (int r = 0; r < 4; ++r) {
            const int o = o0 + fo*16 + sub*4 + r;
            const float ev = E[b*128 + o];
            float sv = 0.f, qv = 0.f;
            #pragma unroll
            for (int ft = 0; ft < 4; ++ft) {
                const float z = acc[fo][ft][r] + ev;
                sv += z; qv += z*z;
            }
            #pragma unroll
            for (int m = 1; m <= 8; m <<= 1) {
                sv += __shfl_xor(sv, m, 64);
                qv += __shfl_xor(qv, m, 64);
            }
            if (li == 0) { sSp[wt][o] = sv; sQp[wt][o] = qv; }
        }
    }
    __syncthreads();
    if (tid < 128) {
        s2p[((size_t)b*NTB + tb)*128 + tid] = sSp[0][tid] + sSp[1][tid];
        q2p[((size_t)b*NTB + tb)*128 + tid] = sQp[0][tid] + sQp[1][tid];
    }
}

// ---------------------------------------------------------------------------
// Kernel D2 (kD1 folded in): per (pg,b) block reduces s2p/q2p -> A2/AE (LDS),
// then F = [conv2*diag(A2*G2)*conv1]*diag(a4) (fp16), h = conv2.AE.
// grid (8 pg, 16 b) x 256 thr.
// ---------------------------------------------------------------------------
__global__ __launch_bounds__(256) void kD2_buildF(
    const float* __restrict__ s2p, const float* __restrict__ q2p,
    const float* __restrict__ ln2_w, const float* __restrict__ ln2_b,
    const float* __restrict__ Ev,
    const float* __restrict__ a4, const float* __restrict__ G2,
    const float* __restrict__ conv1_w, const float* __restrict__ conv2_w,
    ushort* __restrict__ Fsf, float* __restrict__ h)
{
    const int b = blockIdx.y, pg = blockIdx.x;
    const int tid = threadIdx.x;
    __shared__ float Qs[32][128];
    __shared__ float sA2[128], sAE[128];
    __shared__ float rS[2], rQ[2];

    // ---- folded kD1: reduce per-o, then batch-scalar mu/var ----
    float s = 0.f, qq = 0.f;
    if (tid < 128) {
        for (int tb = 0; tb < NTB; ++tb) {
            s  += s2p[((size_t)b*NTB + tb)*128 + tid];
            qq += q2p[((size_t)b*NTB + tb)*128 + tid];
        }
        float S = s, Q = qq;
        #pragma unroll
        for (int off = 32; off; off >>= 1) {
            S += __shfl_down(S, off, 64);
            Q += __shfl_down(Q, off, 64);
        }
        if ((tid & 63) == 0) { rS[tid >> 6] = S; rQ[tid >> 6] = Q; }
    }
    __syncthreads();
    const float N2inv = 1.f / (128.f * 16000.f);
    const float mu  = (rS[0] + rS[1]) * N2inv;
    const float var = (rQ[0] + rQ[1]) * N2inv - mu * mu;
    const float r = rsqrtf(var + EPSV);
    if (tid < 128) {
        const float a2v = ln2_w[tid] * r;
        const float d2v = ln2_b[tid] - mu * ln2_w[tid] * r;
        sA2[tid] = a2v;
        sAE[tid] = a2v * Ev[b*128 + tid] + d2v;
    }
    __syncthreads();

    // ---- F build ----
    #pragma unroll
    for (int k = 0; k < 16; ++k) {
        const int idx = tid + k*256;
        const int p = idx >> 7, o = idx & 127;
        Qs[p][o] = conv2_w[(pg*32 + p)*128 + o] * sA2[o] * G2[b*128 + o];
    }
    __syncthreads();
    float acc[32];
    #pragma unroll
    for (int p = 0; p < 32; ++p) acc[p] = 0.f;
    for (int o = 0; o < 128; ++o) {
        const float mv = conv1_w[o*256 + tid];
        #pragma unroll
        for (int p = 0; p < 32; ++p) acc[p] = fmaf(Qs[p][o], mv, acc[p]);
    }
    const float a = a4[b*256 + tid];
    #pragma unroll
    for (int p = 0; p < 32; ++p) {
        const size_t idx = ((size_t)b*256 + pg*32 + p)*256 + tid;
        Fsf[idx] = f2h(acc[p] * a);
    }
    if (tid < 32) {
        const int p = pg*32 + tid;
        float hv = 0.f;
        for (int o = 0; o < 128; ++o)
            hv += conv2_w[p*128 + o] * sAE[o];
        h[b*256 + p] = hv;
    }
}

// ---------------------------------------------------------------------------
// Kernel E: out = F x + h.  Block 256o x 128t, 4 waves = 4 o-strips.
// B staged via global_load_lds dbuf (2 chunks/buf).  Epilogue reuses Bs as
// per-wave transpose tile -> nontemporal dwordx4 stores (256B runs).
// ---------------------------------------------------------------------------
__global__ __launch_bounds__(256) void kE_gemm(
    const ushort* __restrict__ Xp, const ushort* __restrict__ Fsf,
    const float* __restrict__ h, float* __restrict__ out)
{
    const int tt = blockIdx.x, b = blockIdx.y;     // tt 0..124
    const int tid = threadIdx.x, lane = tid & 63, w = tid >> 6;
    const int sub = lane >> 4, li = lane & 15;
    const int o0 = w * 64, t0 = tt * 128;
    __shared__ __align__(16) ushort Bs[2][8192];   // 2 x 16KB

    const ushort* fp = Fsf + (size_t)b*65536;
    const size_t cbase = ((size_t)b*NTT + 2*tt)*4; // chunk index base

    f32x4 acc[4][8];
    #pragma unroll
    for (int i = 0; i < 4; ++i)
        #pragma unroll
        for (int jx = 0; jx < 8; ++jx) acc[i][jx] = (f32x4){0.f,0.f,0.f,0.f};

    #pragma unroll
    for (int jj = 0; jj < 4; ++jj) {
        const int m = w*4 + jj;                    // 0..15
        const int half = m >> 3, mm = m & 7;
        gld16(Xp + (cbase + half*4 + 0)*4096 + mm*512 + lane*8,
              &Bs[0][half*4096 + mm*512]);
    }
    __syncthreads();
    for (int kc = 0; kc < 4; ++kc) {
        const int buf = kc & 1;
        if (kc < 3) {
            #pragma unroll
            for (int jj = 0; jj < 4; ++jj) {
                const int m = w*4 + jj;
                const int half = m >> 3, mm = m & 7;
                gld16(Xp + (cbase + half*4 + (kc+1))*4096 + mm*512 + lane*8,
                      &Bs[buf^1][half*4096 + mm*512]);
            }
        }
        #pragma unroll
        for (int ks = 0; ks < 2; ++ks) {
            f16x8 bfr[8];
            #pragma unroll
            for (int ft = 0; ft < 8; ++ft) {
                const int t = ft*16 + li;
                const int half = t >> 6, tl = t & 63;
                const int u = (4*ks + sub) ^ (tl & 7);
                bfr[ft] = *(const f16x8*)&Bs[buf][half*4096 + tl*64 + u*8];
            }
            #pragma unroll
            for (int fo = 0; fo < 4; ++fo) {
                const f16x8 a = *(const f16x8*)(fp + (size_t)(o0 + fo*16 + li)*256 + kc*64 + ks*32 + 8*sub);
                #pragma unroll
                for (int ft = 0; ft < 8; ++ft)
                    acc[fo][ft] = __builtin_amdgcn_mfma_f32_16x16x32_f16(a, bfr[ft], acc[fo][ft], 0, 0, 0);
            }
        }
        __syncthreads();
    }

    // epilogue: reuse Bs as per-wave float tile [16][68]
    float* Ts = (float*)(&Bs[0][0]) + w * (16*68);
    #pragma unroll
    for (int fo = 0; fo < 4; ++fo) {
        float hv[4];
        #pragma unroll
        for (int r = 0; r < 4; ++r)
            hv[r] = h[b*256 + o0 + fo*16 + sub*4 + r];
        #pragma unroll
        for (int ph = 0; ph < 2; ++ph) {
            #pragma unroll
            for (int f4 = 0; f4 < 4; ++f4) {
                const int ft = ph*4 + f4;
                #pragma unroll
                for (int r = 0; r < 4; ++r)
                    Ts[(sub*4 + r)*68 + f4*16 + li] = acc[fo][ft][r] + hv[r];
            }
            #pragma unroll
            for (int it = 0; it < 4; ++it) {
                const int row = it*4 + sub;
                const f32x4 v = *(const f32x4*)&Ts[row*68 + li*4];
                __builtin_nontemporal_store(v,
                    (f32x4*)(out + ((size_t)(b*256 + o0 + fo*16 + row))*T_LEN
                             + t0 + ph*64 + li*4));
            }
            // WAR fence: next phase overwrites Ts the reads above used
            asm volatile("s_waitcnt lgkmcnt(0)" ::: "memory");
        }
    }
}

// ---------------------------------------------------------------------------
extern "C" void kernel_launch(void* const* d_in, const int* in_sizes, int n_in,
                              void* d_out, int out_size, void* d_ws, size_t ws_size,
                              hipStream_t stream)
{
    const float* x       = (const float*)d_in[0];
    const float* cue     = (const float*)d_in[1];
    const float* gn_a_w  = (const float*)d_in[2];
    const float* gn_a_b  = (const float*)d_in[3];
    const float* gn_n_w  = (const float*)d_in[4];
    const float* gn_n_b  = (const float*)d_in[5];
    const float* f1g_w   = (const float*)d_in[6];
    const float* f1g_b   = (const float*)d_in[7];
    const float* f1b_w   = (const float*)d_in[8];
    const float* f1b_b   = (const float*)d_in[9];
    const float* ln1_w   = (const float*)d_in[10];
    const float* ln1_b   = (const float*)d_in[11];
    const float* conv1_w = (const float*)d_in[12];
    const float* cds_w   = (const float*)d_in[13];
    const float* f2g_w   = (const float*)d_in[14];
    const float* f2g_b   = (const float*)d_in[15];
    const float* f2b_w   = (const float*)d_in[16];
    const float* f2b_b   = (const float*)d_in[17];
    const float* ln2_w   = (const float*)d_in[18];
    const float* ln2_b   = (const float*)d_in[19];
    const float* conv2_w = (const float*)d_in[20];
    float* out = (float*)d_out;

    float* ws = (float*)d_ws;
    float*  sp   = ws;                       // 1,024,000
    float*  qp   = ws + 1024000;             // 1,024,000
    float*  G1   = ws + 2048000;             // 4,096
    float*  B1   = ws + 2052096;             // 4,096
    float*  CUE2 = ws + 2056192;             // 4,096
    float*  G2   = ws + 2060288;             // 2,048
    float*  a4   = ws + 2062336;             // 4,096
    float*  E    = ws + 2066432;             // 2,048
    float*  h    = ws + 2068480;             // 4,096
    float*  s2p  = ws + 2072576;             // 256,000
    float*  q2p  = ws + 2328576;             // 256,000
    ushort* Msf  = (ushort*)(ws + 2584576);  // 524,288 ush (262,144 f)
    ushort* Fsf  = (ushort*)(ws + 2846720);  // 1,048,576 ush (524,288 f)
    ushort* Xp   = (ushort*)(ws + 3371008);  // 65,536,000 ush
    // total ~ 36,139,008 floats ~= 144.6 MB

    kP1_split<<<dim3(NTT, NB), 256, 0, stream>>>(x, Xp, sp, qp);

    kW1<<<256, 256, 0, stream>>>(cue, f1g_w, f1g_b, f1b_w, f1b_b, cds_w,
                                 G1, B1, CUE2);

    kBM<<<NB, 256, 0, stream>>>(sp, qp, gn_a_w, gn_a_b, gn_n_w, gn_n_b,
                                G1, B1, ln1_w, ln1_b, CUE2,
                                f2g_w, f2g_b, f2b_w, f2b_b, conv1_w,
                                a4, G2, E, Msf);

    kC_gemm<<<dim3(NTB, NB), 256, 0, stream>>>(Xp, Msf, E, s2p, q2p);

    kD2_buildF<<<dim3(8, NB), 256, 0, stream>>>(s2p, q2p, ln2_w, ln2_b, E,
                                                a4, G2, conv1_w, conv2_w,
                                                Fsf, h);

    kE_gemm<<<dim3(NTB, NB), 256, 0, stream>>>(Xp, Fsf, h, out);
}